// Round 11
// baseline (194.033 us; speedup 1.0000x reference)
//
#include <hip/hip_runtime.h>
#include <cstdint>
#include <cstddef>

#define NB 2
#define NN 4096
#define ND 256
#define TRI 528   // 32*33/2 causal 128-tiles per (batch, mat)

typedef __attribute__((ext_vector_type(8))) _Float16 half8;
typedef __attribute__((ext_vector_type(4))) _Float16 half4;
typedef __attribute__((ext_vector_type(4))) float f32x4;

using gas_ptr = const __attribute__((address_space(1))) void*;
using las_ptr = __attribute__((address_space(3))) void*;

__device__ __host__ __forceinline__ int tri32(int t) { return t * (t + 1) / 2; }

__device__ __forceinline__ f32x4 mfma_16x16x32(half8 a, half8 b, f32x4 c) {
    return __builtin_amdgcn_mfma_f32_16x16x32_f16(a, b, c, 0, 0, 0);
}

#define BAR_V4() asm volatile("s_waitcnt vmcnt(4) lgkmcnt(0)\n\ts_barrier" ::: "memory")
#define BAR_V0() asm volatile("s_waitcnt vmcnt(0) lgkmcnt(0)\n\ts_barrier" ::: "memory")

// ---- 128-row x 64B staging side, paired-row swizzle (2 logical rows / 128B) ----
__device__ __forceinline__ void stage_side(const char* __restrict__ gb, size_t rstride,
                                           char* lb) {
    #pragma unroll
    for (int i = 0; i < 2; ++i) {
        const int o = threadIdx.x * 16 + i * 4096;
        const int rp = o >> 7;
        const int uw = (o & 127) ^ ((rp & 7) << 4);
        const int r = rp * 2 + (uw >> 6);
        const int c = uw & 63;
        __builtin_amdgcn_global_load_lds((gas_ptr)(gb + (size_t)r * rstride + c),
                                         (las_ptr)(lb + o), 16, 0, 0);
    }
}

__device__ __forceinline__ half8 ldsfrag(const char* lb, int row, int lg) {
    const int rp = row >> 1;
    const int x = (((row & 1) << 6) + (lg << 4)) ^ ((rp & 7) << 4);
    return *(const half8*)(lb + rp * 128 + x);
}

// ---------------- conversions ----------------
__global__ __launch_bounds__(256) void k_cvt_h(const float* __restrict__ h,
                                               _Float16* __restrict__ h16) {
    const int i = blockIdx.x * 256 + threadIdx.x;
    f32x4 v = ((const f32x4*)h)[i];
    half4 o;
    o[0] = (_Float16)v[0]; o[1] = (_Float16)v[1];
    o[2] = (_Float16)v[2]; o[3] = (_Float16)v[3];
    ((half4*)h16)[i] = o;
}

__global__ __launch_bounds__(256) void k_wt(const float* __restrict__ W0, const float* __restrict__ W1,
                                            const float* __restrict__ W2, const float* __restrict__ W3,
                                            _Float16* __restrict__ T0, _Float16* __restrict__ T1,
                                            _Float16* __restrict__ T2, _Float16* __restrict__ T3) {
    const int m = blockIdx.y;
    const float* W = m == 0 ? W0 : m == 1 ? W1 : m == 2 ? W2 : W3;
    _Float16* T    = m == 0 ? T0 : m == 1 ? T1 : m == 2 ? T2 : T3;
    const int k = blockIdx.x, j = threadIdx.x;
    T[j * ND + k] = (_Float16)W[k * ND + j];
}

// ---------------- GEMM core (projections / output) ----------------
__device__ __forceinline__ void gemm_core(const _Float16* __restrict__ A,
                                          const _Float16* __restrict__ Bt,
                                          int row0, int l16, int lg, f32x4 acc[16]) {
    #pragma unroll
    for (int i = 0; i < 16; ++i) acc[i] = (f32x4)0.0f;
    #pragma unroll
    for (int ks = 0; ks < 8; ++ks) {
        half8 a = *(const half8*)(A + (size_t)(row0 + l16) * ND + ks * 32 + lg * 8);
        #pragma unroll
        for (int ct = 0; ct < 16; ++ct) {
            half8 b = *(const half8*)(Bt + (size_t)(ct * 16 + l16) * ND + ks * 32 + lg * 8);
            acc[ct] = mfma_16x16x32(a, b, acc[ct]);
        }
    }
}

// modes: 0 -> zn (normalized), 1 -> zg + sq, 2 -> vT (transposed via LDS bounce)
__global__ __launch_bounds__(256) void k_proj(const _Float16* __restrict__ h16,
                                              const _Float16* __restrict__ Wlt,
                                              const _Float16* __restrict__ Wgt,
                                              const _Float16* __restrict__ Wvt,
                                              _Float16* __restrict__ zn,
                                              _Float16* __restrict__ zg,
                                              _Float16* __restrict__ vT,
                                              float* __restrict__ sq) {
    const int mode = blockIdx.y;
    const _Float16* Bt = mode == 0 ? Wlt : mode == 1 ? Wgt : Wvt;
    __shared__ _Float16 t[64][266];          // mode-2 transpose bounce (pad 266: conflict-free cols)
    const int w = threadIdx.x >> 6, l = threadIdx.x & 63;
    const int l16 = l & 15, lg = l >> 4;
    const int row0 = blockIdx.x * 64 + w * 16;
    f32x4 acc[16];
    gemm_core(h16, Bt, row0, l16, lg, acc);

    if (mode == 2) {
        #pragma unroll
        for (int ct = 0; ct < 16; ++ct)
            #pragma unroll
            for (int r = 0; r < 4; ++r)
                t[w * 16 + lg * 4 + r][ct * 16 + l16] = (_Float16)acc[ct][r];
        __syncthreads();
        const int base = blockIdx.x * 64;
        const int b = base >> 12, n0 = base & 4095;
        #pragma unroll
        for (int it = 0; it < 64; ++it) {
            const int d = it * 4 + (threadIdx.x >> 6);
            vT[((size_t)b * ND + d) * NN + n0 + (threadIdx.x & 63)] = t[threadIdx.x & 63][d];
        }
        return;
    }
    _Float16* o16 = mode == 0 ? zn : zg;
    float n2[4] = {0.f, 0.f, 0.f, 0.f};
    #pragma unroll
    for (int ct = 0; ct < 16; ++ct)
        #pragma unroll
        for (int r = 0; r < 4; ++r) n2[r] += acc[ct][r] * acc[ct][r];
    #pragma unroll
    for (int m = 1; m < 16; m <<= 1) {
        #pragma unroll
        for (int r = 0; r < 4; ++r) n2[r] += __shfl_xor(n2[r], m);
    }
    if (mode == 0) {
        float ri[4];
        #pragma unroll
        for (int r = 0; r < 4; ++r) ri[r] = 1.0f / fmaxf(sqrtf(n2[r]), 1e-8f);
        #pragma unroll
        for (int ct = 0; ct < 16; ++ct)
            #pragma unroll
            for (int r = 0; r < 4; ++r)
                o16[(size_t)(row0 + lg * 4 + r) * ND + ct * 16 + l16] =
                    (_Float16)(acc[ct][r] * ri[r]);
    } else {
        #pragma unroll
        for (int ct = 0; ct < 16; ++ct)
            #pragma unroll
            for (int r = 0; r < 4; ++r)
                o16[(size_t)(row0 + lg * 4 + r) * ND + ct * 16 + l16] = (_Float16)acc[ct][r];
        if (l16 == 0) {
            #pragma unroll
            for (int r = 0; r < 4; ++r) sq[row0 + lg * 4 + r] = n2[r];
        }
    }
}

// ---------------- score GEMM (R7 structure + XCD swizzle + setprio) -------------
// One 128-tile per block, BK=32, tri-buffer, counted vmcnt(4). Grid 2112 flat.
__global__ __launch_bounds__(256, 3) void k_score(const _Float16* __restrict__ zn,
                                                  const _Float16* __restrict__ zg,
                                                  const float* __restrict__ sqg,
                                                  _Float16* __restrict__ P,
                                                  float* __restrict__ degpart) {
    const int orig = blockIdx.x;
    const int wgid = (orig & 7) * (NB * 2 * TRI / 8) + (orig >> 3);  // bijective XCD swizzle
    const int bm = wgid / TRI;
    int x = wgid % TRI, tq = 0;
    while (x > tq) { x -= (tq + 1); ++tq; }
    const int tk = x;
    const int b = bm >> 1, mat = bm & 1;
    const char* z = (const char*)((mat ? zg : zn) + (size_t)b * NN * ND);
    const float* sqb = sqg + (size_t)b * NN;
    const int w = threadIdx.x >> 6, lane = threadIdx.x & 63;
    const int l16 = lane & 15, lg = lane >> 4;
    const int wr = w >> 1, wc = w & 1;

    __shared__ char At[3][8192], Bq[3][8192];

    const char* zk = z + (size_t)tk * 128 * 512;
    const char* zq = z + (size_t)tq * 128 * 512;

    auto STAGE = [&](int bufi, int s_) {
        stage_side(zk + s_ * 64, 512, &At[bufi][0]);
        stage_side(zq + s_ * 64, 512, &Bq[bufi][0]);
    };

    f32x4 acc[4][4];
    #pragma unroll
    for (int i = 0; i < 4; ++i)
        #pragma unroll
        for (int j = 0; j < 4; ++j) acc[i][j] = (f32x4)0.f;

    STAGE(0, 0);
    STAGE(1, 1);
    BAR_V4();                                  // stage(0) landed; stage(1) in flight

    #pragma unroll
    for (int s = 0; s < 8; ++s) {
        if (s < 6) STAGE((s + 2) % 3, s + 2);
        const int cb = s % 3;
        half8 a[4], bq[4];
        #pragma unroll
        for (int i = 0; i < 4; ++i) {
            a[i]  = ldsfrag(&At[cb][0], wr * 64 + i * 16 + l16, lg);
            bq[i] = ldsfrag(&Bq[cb][0], wc * 64 + i * 16 + l16, lg);
        }
        __builtin_amdgcn_s_setprio(1);
        #pragma unroll
        for (int di = 0; di < 4; ++di)
            #pragma unroll
            for (int qi = 0; qi < 4; ++qi)
                acc[di][qi] = mfma_16x16x32(a[di], bq[qi], acc[di][qi]);
        __builtin_amdgcn_s_setprio(0);
        if (s < 6) BAR_V4();
        else if (s == 6) BAR_V0();
    }

    // ---- epilogue: transform, P write, degree partials
    const int tile = tri32(tq) + tk;
    _Float16* Pt = P + (size_t)(bm * TRI + tile) * 16384;
    float dsum[4] = {0.f, 0.f, 0.f, 0.f};
    float sqq[4];
    if (mat) {
        #pragma unroll
        for (int qi = 0; qi < 4; ++qi)
            sqq[qi] = sqb[tq * 128 + wc * 64 + qi * 16 + l16];
    }
    #pragma unroll
    for (int di = 0; di < 4; ++di) {
        const int kl = wr * 64 + di * 16 + lg * 4;
        const int kg = tk * 128 + kl;
        f32x4 sqk;
        if (mat) sqk = *(const f32x4*)(sqb + kg);
        #pragma unroll
        for (int qi = 0; qi < 4; ++qi) {
            const int qg = tq * 128 + wc * 64 + qi * 16 + l16;
            half4 hv;
            #pragma unroll
            for (int r = 0; r < 4; ++r) {
                const bool msk = (kg + r) < qg;        // causal + zero-diag
                float p;
                if (mat) p = msk ? __expf(-0.5f * (sqq[qi] + sqk[r] - 2.f * acc[di][qi][r])) : 0.f;
                else     p = msk ? fmaxf(acc[di][qi][r], 0.f) : 0.f;
                dsum[qi] += p;
                hv[r] = (_Float16)p;
            }
            *(half4*)(Pt + (size_t)(wc * 64 + qi * 16 + l16) * 128 + kl) = hv;
        }
    }
    #pragma unroll
    for (int qi = 0; qi < 4; ++qi) {
        dsum[qi] += __shfl_xor(dsum[qi], 16);
        dsum[qi] += __shfl_xor(dsum[qi], 32);
    }
    if (lg == 0) {
        #pragma unroll
        for (int qi = 0; qi < 4; ++qi)
            degpart[(size_t)(bm * TRI + tile) * 256 + wr * 128 + wc * 64 + qi * 16 + l16] = dsum[qi];
    }
}

// ---------------- deg: sum tile partials -> normalized weights ----------------
__global__ __launch_bounds__(128) void k_deg(const float* __restrict__ degpart,
                                             float* __restrict__ rln,
                                             float* __restrict__ rgn) {
    const int bm = blockIdx.x >> 5, tq = blockIdx.x & 31;
    const int b = bm >> 1, mat = bm & 1;
    const float* dp = degpart + (size_t)(bm * TRI + tri32(tq)) * 256 + threadIdx.x;
    float s = 0.f;
    for (int tk = 0; tk <= tq; ++tk)
        s += dp[(size_t)tk * 256] + dp[(size_t)tk * 256 + 128];
    const float r = (mat ? 0.1f : 0.9f) / fmaxf(s, 1e-8f);   // T_WAKE weights
    (mat ? rgn : rln)[(size_t)b * NN + tq * 128 + threadIdx.x] = r;
}

// ---------------- PV GEMM v4: merged-mat B (rl*Pl + rg*Pg staged in regs) --------
// Block = (b, dh, tq, tk-chunk). A = vT (global_load_lds), B = merged P (reg-staged,
// T14 split: loads 2 steps ahead, vmcnt(6) wait, f32 merge, ds_write). One GEMM.
#define PV_ISSUE(J, IL, IG) do {                                               \
    const int j_i = (J); const int kt_i = kt0 + (j_i >> 2), sub_i = j_i & 3;   \
    stage_side(vTb + (size_t)kt_i * 256 + sub_i * 64, (size_t)NN * 2,          \
               &At[j_i % 3][0]);                                               \
    _Pragma("unroll")                                                          \
    for (int i = 0; i < 2; ++i) {                                              \
        const int o = threadIdx.x * 16 + i * 4096;                             \
        const int rp = o >> 7;                                                 \
        const int uw = (o & 127) ^ ((rp & 7) << 4);                            \
        const int cB = uw & 63;                                                \
        const size_t so = (size_t)kt_i * 32768 + rr[i] * 256 + sub_i * 64 + cB;\
        IL[i] = *(const half8*)(Pl0 + so);                                     \
        IG[i] = *(const half8*)(Pg0 + so);                                     \
    }                                                                          \
} while (0)

#define PV_WRITE(J, WL, WG) do {                                               \
    const int j_w = (J);                                                       \
    _Pragma("unroll")                                                          \
    for (int i = 0; i < 2; ++i) {                                              \
        const int o = threadIdx.x * 16 + i * 4096;                             \
        half8 pm;                                                              \
        _Pragma("unroll")                                                      \
        for (int k = 0; k < 8; ++k)                                            \
            pm[k] = (_Float16)(rlv[i] * (float)WL[i][k] +                      \
                               rgv[i] * (float)WG[i][k]);                      \
        *(half8*)(&Bp[j_w % 3][0] + o) = pm;                                   \
    }                                                                          \
} while (0)

#define PV_STEP(S, IL, IG, WL, WG) do {                                        \
    const int s_ = (S);                                                        \
    if (s_ + 2 < NS) PV_ISSUE(s_ + 2, IL, IG);                                 \
    {                                                                          \
        const int cb = s_ % 3;                                                 \
        half8 a[4], bp[4];                                                     \
        _Pragma("unroll")                                                      \
        for (int i = 0; i < 4; ++i) {                                          \
            a[i]  = ldsfrag(&At[cb][0], wr * 64 + i * 16 + l16, lg);           \
            bp[i] = ldsfrag(&Bp[cb][0], wc * 64 + i * 16 + l16, lg);           \
        }                                                                      \
        __builtin_amdgcn_s_setprio(1);                                         \
        _Pragma("unroll")                                                      \
        for (int di = 0; di < 4; ++di)                                         \
            _Pragma("unroll")                                                  \
            for (int qi = 0; qi < 4; ++qi)                                     \
                acc[di][qi] = mfma_16x16x32(a[di], bp[qi], acc[di][qi]);       \
        __builtin_amdgcn_s_setprio(0);                                         \
    }                                                                          \
    if (s_ + 1 < NS) {                                                         \
        if (s_ + 2 < NS) asm volatile("s_waitcnt vmcnt(6)" ::: "memory");      \
        else             asm volatile("s_waitcnt vmcnt(0)" ::: "memory");      \
        PV_WRITE(s_ + 1, WL, WG);                                              \
        asm volatile("s_waitcnt lgkmcnt(0)\n\ts_barrier" ::: "memory");        \
    }                                                                          \
} while (0)

__global__ __launch_bounds__(256, 2) void k_pv(const _Float16* __restrict__ P,
                                               const _Float16* __restrict__ vT,
                                               const float* __restrict__ rln,
                                               const float* __restrict__ rgn,
                                               _Float16* __restrict__ part,
                                               int CHUNK, int NCH, int swz) {
    const int orig = blockIdx.x;
    const int nper = gridDim.x >> 3;
    const int wgid = swz ? ((orig & 7) * nper + (orig >> 3)) : orig;
    const int b = wgid / (2 * NCH);
    const int rem = wgid % (2 * NCH);
    const int dh = rem / NCH;
    int x = NCH - 1 - (rem % NCH);           // reversed: long chunks first
    int tq = 0, cum = 0;
    for (;;) {
        const int nc = (tq + CHUNK) / CHUNK;
        if (x < nc) break;
        x -= nc; cum += nc; ++tq;
    }
    const int c = x;
    const int kt0 = c * CHUNK;
    const int ktE = (kt0 + CHUNK < tq + 1) ? kt0 + CHUNK : tq + 1;
    const int NS = (ktE - kt0) * 4;          // BK=32 steps (multiple of 4)

    const int w = threadIdx.x >> 6, lane = threadIdx.x & 63;
    const int l16 = lane & 15, lg = lane >> 4;
    const int wr = w >> 1, wc = w & 1;

    __shared__ char At[3][8192], Bp[3][8192];

    const char* vTb = (const char*)(vT + (size_t)b * ND * NN) + (size_t)dh * 128 * (NN * 2);
    const char* Pl0 = (const char*)(P + (size_t)((b * 2 + 0) * TRI + tri32(tq)) * 16384);
    const char* Pg0 = (const char*)(P + (size_t)((b * 2 + 1) * TRI + tri32(tq)) * 16384);

    // per-thread fixed staging rows + their normalized weights
    int rr[2]; float rlv[2], rgv[2];
    #pragma unroll
    for (int i = 0; i < 2; ++i) {
        const int o = threadIdx.x * 16 + i * 4096;
        const int rp = o >> 7;
        const int uw = (o & 127) ^ ((rp & 7) << 4);
        rr[i] = rp * 2 + (uw >> 6);
        rlv[i] = rln[(size_t)b * NN + tq * 128 + rr[i]];
        rgv[i] = rgn[(size_t)b * NN + tq * 128 + rr[i]];
    }

    f32x4 acc[4][4];
    #pragma unroll
    for (int i = 0; i < 4; ++i)
        #pragma unroll
        for (int j = 0; j < 4; ++j) acc[i][j] = (f32x4)0.f;

    half8 l0[2], g0[2], l1[2], g1[2];
    PV_ISSUE(0, l0, g0);
    PV_ISSUE(1, l1, g1);
    asm volatile("s_waitcnt vmcnt(6)" ::: "memory");   // stage(0) landed
    PV_WRITE(0, l0, g0);
    asm volatile("s_waitcnt lgkmcnt(0)\n\ts_barrier" ::: "memory");

    for (int s = 0; s < NS; s += 2) {
        PV_STEP(s,     l0, g0, l1, g1);      // issue (s+2)->set0, write (s+1) from set1
        PV_STEP(s + 1, l1, g1, l0, g0);      // issue (s+3)->set1, write (s+2) from set0
    }

    _Float16* sl = part + (size_t)((b * NCH + cum + c) * 2 + dh) * 16384;
    #pragma unroll
    for (int di = 0; di < 4; ++di) {
        const int dl = wr * 64 + di * 16 + lg * 4;
        #pragma unroll
        for (int qi = 0; qi < 4; ++qi) {
            half4 hv;
            #pragma unroll
            for (int r = 0; r < 4; ++r) hv[r] = (_Float16)acc[di][qi][r];
            *(half4*)(sl + (size_t)(wc * 64 + qi * 16 + l16) * 128 + dl) = hv;
        }
    }
}

// ---------------- combine (pre-normalized) partials + @Wo -> out ----------------
__global__ __launch_bounds__(512) void k_combo(const _Float16* __restrict__ part,
                                               const _Float16* __restrict__ Wot,
                                               float* __restrict__ out,
                                               int CHUNK, int NCH) {
    const int tq = blockIdx.x, b = blockIdx.y;
    __shared__ _Float16 ot_t[128][264];      // 528B rows (16B-aligned)
    int cum = 0;
    for (int t = 0; t < tq; ++t) cum += (t + CHUNK) / CHUNK;
    const int nc = (tq + CHUNK) / CHUNK;
    #pragma unroll
    for (int it = 0; it < 8; ++it) {
        const int f = it * 4096 + threadIdx.x * 8;   // 32768 f16 total
        const int dh = f >> 14, rem = f & 16383;
        const int row = rem >> 7, col = rem & 127;
        float s[8] = {0,0,0,0,0,0,0,0};
        for (int c = 0; c < nc; ++c) {
            half8 xv = *(const half8*)(part +
                (size_t)((b * NCH + cum + c) * 2 + dh) * 16384 + rem);
            #pragma unroll
            for (int k = 0; k < 8; ++k) s[k] += (float)xv[k];
        }
        half8 o;
        #pragma unroll
        for (int k = 0; k < 8; ++k) o[k] = (_Float16)s[k];
        *(half8*)&ot_t[row][dh * 128 + col] = o;
    }
    __syncthreads();

    const int w = threadIdx.x >> 6, l = threadIdx.x & 63;
    const int l16 = l & 15, lg = l >> 4;
    const int row0 = w * 16;
    f32x4 acc[16];
    #pragma unroll
    for (int i = 0; i < 16; ++i) acc[i] = (f32x4)0.f;
    #pragma unroll
    for (int ks = 0; ks < 8; ++ks) {
        half8 a = *(const half8*)&ot_t[row0 + l16][ks * 32 + lg * 8];
        #pragma unroll
        for (int ct = 0; ct < 16; ++ct) {
            half8 bw = *(const half8*)(Wot + (size_t)(ct * 16 + l16) * ND + ks * 32 + lg * 8);
            acc[ct] = mfma_16x16x32(a, bw, acc[ct]);
        }
    }
    #pragma unroll
    for (int ct = 0; ct < 16; ++ct)
        #pragma unroll
        for (int r = 0; r < 4; ++r)
            out[(size_t)(b * NN + tq * 128 + row0 + lg * 4 + r) * ND + ct * 16 + l16] = acc[ct][r];
}

extern "C" void kernel_launch(void* const* d_in, const int* in_sizes, int n_in,
                              void* d_out, int out_size, void* d_ws, size_t ws_size,
                              hipStream_t stream) {
    const float* h  = (const float*)d_in[0];
    const float* Wl = (const float*)d_in[2];
    const float* Wg = (const float*)d_in[3];
    const float* Wv = (const float*)d_in[4];
    const float* Wo = (const float*)d_in[5];
    float* out = (float*)d_out;

    uint8_t* base = (uint8_t*)d_ws;
    size_t off = 0;
    auto alloc = [&](size_t bytes) -> void* {
        void* r = base + off;
        off = (off + bytes + 255) & ~(size_t)255;
        return r;
    };
    const size_t bnd = (size_t)NB * NN * ND;
    _Float16* h16 = (_Float16*)alloc(bnd * 2);
    _Float16* Wlt = (_Float16*)alloc(ND * ND * 2);
    _Float16* Wgt = (_Float16*)alloc(ND * ND * 2);
    _Float16* Wvt = (_Float16*)alloc(ND * ND * 2);
    _Float16* Wot = (_Float16*)alloc(ND * ND * 2);
    _Float16* zn  = (_Float16*)alloc(bnd * 2);
    _Float16* zg  = (_Float16*)alloc(bnd * 2);
    _Float16* vT  = (_Float16*)alloc(bnd * 2);
    float*    sq  = (float*)alloc((size_t)NB * NN * 4);
    _Float16* P   = (_Float16*)alloc((size_t)NB * 2 * TRI * 16384 * 2);   // 69 MB
    float* degpart = (float*)alloc((size_t)NB * 2 * TRI * 256 * 4);       // 2.2 MB
    float* rln = (float*)alloc((size_t)NB * NN * 4);
    float* rgn = (float*)alloc((size_t)NB * NN * 4);

    // split-K chunking with ws fallback (part: NB*NCH*2 slots x 32KB)
    int CHUNK = 4, NCH = 0;
    for (;;) {
        NCH = 0;
        for (int t = 0; t < 32; ++t) NCH += (t + CHUNK) / CHUNK;
        if (off + (size_t)NB * NCH * 2 * 16384 * 2 + 256 <= ws_size || CHUNK >= 32) break;
        CHUNK *= 2;
    }
    _Float16* part = (_Float16*)alloc((size_t)NB * NCH * 2 * 16384 * 2);
    const int pv_grid = NB * 2 * NCH;
    const int pv_swz = (pv_grid % 8 == 0) ? 1 : 0;

    k_cvt_h<<<bnd / 4 / 256, 256, 0, stream>>>(h, h16);
    k_wt<<<dim3(ND, 4), 256, 0, stream>>>(Wl, Wg, Wv, Wo, Wlt, Wgt, Wvt, Wot);
    k_proj<<<dim3(NB * NN / 64, 3), 256, 0, stream>>>(h16, Wlt, Wgt, Wvt, zn, zg, vT, sq);
    k_score<<<NB * 2 * TRI, 256, 0, stream>>>(zn, zg, sq, P, degpart);
    k_deg<<<NB * 2 * 32, 128, 0, stream>>>(degpart, rln, rgn);
    k_pv<<<pv_grid, 256, 0, stream>>>(P, vT, rln, rgn, part, CHUNK, NCH, pv_swz);
    k_combo<<<dim3(32, NB), 512, 0, stream>>>(part, Wot, out, CHUNK, NCH);
}

// Round 12
// 193.317 us; speedup vs baseline: 1.0037x; 1.0037x over previous
//
#include <hip/hip_runtime.h>
#include <cstdint>
#include <cstddef>

#define NB 2
#define NN 4096
#define ND 256
#define TRI 528   // 32*33/2 causal 128-tiles per (batch, mat)
#define NPAIR 272 // sum over tq of ceil((tq+1)/2)

typedef __attribute__((ext_vector_type(8))) _Float16 half8;
typedef __attribute__((ext_vector_type(4))) _Float16 half4;
typedef __attribute__((ext_vector_type(4))) float f32x4;

using gas_ptr = const __attribute__((address_space(1))) void*;
using las_ptr = __attribute__((address_space(3))) void*;

__device__ __host__ __forceinline__ int tri32(int t) { return t * (t + 1) / 2; }

__device__ __forceinline__ f32x4 mfma_16x16x32(half8 a, half8 b, f32x4 c) {
    return __builtin_amdgcn_mfma_f32_16x16x32_f16(a, b, c, 0, 0, 0);
}

#define BAR_V4() asm volatile("s_waitcnt vmcnt(4) lgkmcnt(0)\n\ts_barrier" ::: "memory")
#define BAR_V0() asm volatile("s_waitcnt vmcnt(0) lgkmcnt(0)\n\ts_barrier" ::: "memory")

// ---- 128-row x 64B staging side, paired-row swizzle (2 logical rows / 128B) ----
__device__ __forceinline__ void stage_side(const char* __restrict__ gb, size_t rstride,
                                           char* lb) {
    #pragma unroll
    for (int i = 0; i < 2; ++i) {
        const int o = threadIdx.x * 16 + i * 4096;
        const int rp = o >> 7;
        const int uw = (o & 127) ^ ((rp & 7) << 4);
        const int r = rp * 2 + (uw >> 6);
        const int c = uw & 63;
        __builtin_amdgcn_global_load_lds((gas_ptr)(gb + (size_t)r * rstride + c),
                                         (las_ptr)(lb + o), 16, 0, 0);
    }
}

__device__ __forceinline__ half8 ldsfrag(const char* lb, int row, int lg) {
    const int rp = row >> 1;
    const int x = (((row & 1) << 6) + (lg << 4)) ^ ((rp & 7) << 4);
    return *(const half8*)(lb + rp * 128 + x);
}

// ---------------- conversions ----------------
__global__ __launch_bounds__(256) void k_cvt_h(const float* __restrict__ h,
                                               _Float16* __restrict__ h16) {
    const int i = blockIdx.x * 256 + threadIdx.x;
    f32x4 v = ((const f32x4*)h)[i];
    half4 o;
    o[0] = (_Float16)v[0]; o[1] = (_Float16)v[1];
    o[2] = (_Float16)v[2]; o[3] = (_Float16)v[3];
    ((half4*)h16)[i] = o;
}

__global__ __launch_bounds__(256) void k_wt(const float* __restrict__ W0, const float* __restrict__ W1,
                                            const float* __restrict__ W2, const float* __restrict__ W3,
                                            _Float16* __restrict__ T0, _Float16* __restrict__ T1,
                                            _Float16* __restrict__ T2, _Float16* __restrict__ T3) {
    const int m = blockIdx.y;
    const float* W = m == 0 ? W0 : m == 1 ? W1 : m == 2 ? W2 : W3;
    _Float16* T    = m == 0 ? T0 : m == 1 ? T1 : m == 2 ? T2 : T3;
    const int k = blockIdx.x, j = threadIdx.x;
    T[j * ND + k] = (_Float16)W[k * ND + j];
}

// ---------------- GEMM core (projections) ----------------
__device__ __forceinline__ void gemm_core(const _Float16* __restrict__ A,
                                          const _Float16* __restrict__ Bt,
                                          int row0, int l16, int lg, f32x4 acc[16]) {
    #pragma unroll
    for (int i = 0; i < 16; ++i) acc[i] = (f32x4)0.0f;
    #pragma unroll
    for (int ks = 0; ks < 8; ++ks) {
        half8 a = *(const half8*)(A + (size_t)(row0 + l16) * ND + ks * 32 + lg * 8);
        #pragma unroll
        for (int ct = 0; ct < 16; ++ct) {
            half8 b = *(const half8*)(Bt + (size_t)(ct * 16 + l16) * ND + ks * 32 + lg * 8);
            acc[ct] = mfma_16x16x32(a, b, acc[ct]);
        }
    }
}

__global__ __launch_bounds__(256) void k_proj(const _Float16* __restrict__ h16,
                                              const _Float16* __restrict__ Wlt,
                                              const _Float16* __restrict__ Wgt,
                                              const _Float16* __restrict__ Wvt,
                                              _Float16* __restrict__ zn,
                                              _Float16* __restrict__ zg,
                                              _Float16* __restrict__ v16,
                                              float* __restrict__ sq) {
    const int mode = blockIdx.y;
    const _Float16* Bt = mode == 0 ? Wlt : mode == 1 ? Wgt : Wvt;
    _Float16* o16      = mode == 0 ? zn  : mode == 1 ? zg  : v16;
    const int w = threadIdx.x >> 6, l = threadIdx.x & 63;
    const int l16 = l & 15, lg = l >> 4;
    const int row0 = blockIdx.x * 64 + w * 16;
    f32x4 acc[16];
    gemm_core(h16, Bt, row0, l16, lg, acc);

    if (mode == 2) {
        #pragma unroll
        for (int ct = 0; ct < 16; ++ct)
            #pragma unroll
            for (int r = 0; r < 4; ++r)
                o16[(size_t)(row0 + lg * 4 + r) * ND + ct * 16 + l16] = (_Float16)acc[ct][r];
        return;
    }
    float n2[4] = {0.f, 0.f, 0.f, 0.f};
    #pragma unroll
    for (int ct = 0; ct < 16; ++ct)
        #pragma unroll
        for (int r = 0; r < 4; ++r) n2[r] += acc[ct][r] * acc[ct][r];
    #pragma unroll
    for (int m = 1; m < 16; m <<= 1) {
        #pragma unroll
        for (int r = 0; r < 4; ++r) n2[r] += __shfl_xor(n2[r], m);
    }
    if (mode == 0) {
        float ri[4];
        #pragma unroll
        for (int r = 0; r < 4; ++r) ri[r] = 1.0f / fmaxf(sqrtf(n2[r]), 1e-8f);
        #pragma unroll
        for (int ct = 0; ct < 16; ++ct)
            #pragma unroll
            for (int r = 0; r < 4; ++r)
                o16[(size_t)(row0 + lg * 4 + r) * ND + ct * 16 + l16] =
                    (_Float16)(acc[ct][r] * ri[r]);
    } else {
        #pragma unroll
        for (int ct = 0; ct < 16; ++ct)
            #pragma unroll
            for (int r = 0; r < 4; ++r)
                o16[(size_t)(row0 + lg * 4 + r) * ND + ct * 16 + l16] = (_Float16)acc[ct][r];
        if (l16 == 0) {
            #pragma unroll
            for (int r = 0; r < 4; ++r) sq[row0 + lg * 4 + r] = n2[r];
        }
    }
}

// v16 [b][n][d] -> vT [b][d][n]
__global__ __launch_bounds__(256) void k_tr(const _Float16* __restrict__ v16,
                                            _Float16* __restrict__ vT) {
    __shared__ _Float16 t[64][72];
    const int b = blockIdx.z, n0 = blockIdx.x * 64, d0 = blockIdx.y * 64;
    const int tj = threadIdx.x & 63, ti = threadIdx.x >> 6;
    #pragma unroll
    for (int i = 0; i < 16; ++i)
        t[ti + i * 4][tj] = v16[(size_t)(b * NN + n0 + ti + i * 4) * ND + d0 + tj];
    __syncthreads();
    #pragma unroll
    for (int i = 0; i < 16; ++i)
        vT[(size_t)(b * ND + d0 + ti + i * 4) * NN + n0 + tj] = t[tj][ti + i * 4];
}

// ---------------- score GEMM v6: sequential tk-pair per block ----------------
// grid 1088 = 4 bm x 272 pairs (XCD bijective swizzle). Block computes tiles
// (tq,tk0) then (tq,tk0+1) back-to-back: 16 BK=32 steps through one tri-buffered
// pipeline (counted vmcnt(4)); epilogue of tile0 at step 7 overlaps the in-flight
// stages of tile1. Singletons duplicate-compute tile0 and skip the dup epilogue.
__global__ __launch_bounds__(256, 3) void k_score(const _Float16* __restrict__ zn,
                                                  const _Float16* __restrict__ zg,
                                                  const float* __restrict__ sqg,
                                                  _Float16* __restrict__ P,
                                                  float* __restrict__ degpart) {
    const int orig = blockIdx.x;
    const int wgid = (orig & 7) * (NB * 2 * NPAIR / 8) + (orig >> 3);  // bijective XCD swizzle
    const int bm = wgid / NPAIR;
    int s = wgid % NPAIR;
    int tq = 0;
    while (s >= (tq + 2) / 2) { s -= (tq + 2) / 2; ++tq; }
    const int tk0 = 2 * s;
    const bool has1 = (tk0 + 1) <= tq;
    const int tk1 = has1 ? tk0 + 1 : tk0;
    const int b = bm >> 1, mat = bm & 1;
    const char* z = (const char*)((mat ? zg : zn) + (size_t)b * NN * ND);
    const float* sqb = sqg + (size_t)b * NN;
    const int w = threadIdx.x >> 6, lane = threadIdx.x & 63;
    const int l16 = lane & 15, lg = lane >> 4;
    const int wr = w >> 1, wc = w & 1;

    __shared__ char At[3][8192], Bq[3][8192];

    const char* zq = z + (size_t)tq * 65536;
    const char* zk[2] = { z + (size_t)tk0 * 65536, z + (size_t)tk1 * 65536 };

    auto STAGE = [&](int bufi, int j_) {
        stage_side(zk[j_ >> 3] + (j_ & 7) * 64, 512, &At[bufi][0]);
        stage_side(zq + (j_ & 7) * 64, 512, &Bq[bufi][0]);
    };

    f32x4 acc[4][4];
    #pragma unroll
    for (int i = 0; i < 4; ++i)
        #pragma unroll
        for (int j = 0; j < 4; ++j) acc[i][j] = (f32x4)0.f;

    float sqq[4];
    if (mat) {
        #pragma unroll
        for (int qi = 0; qi < 4; ++qi)
            sqq[qi] = sqb[tq * 128 + wc * 64 + qi * 16 + l16];
    }

    // epilogue: transform acc -> P tile + degree partials, re-zero acc
    auto EPI = [&](int tk) {
        const int tile = tri32(tq) + tk;
        _Float16* Pt = P + (size_t)(bm * TRI + tile) * 16384;
        float dsum[4] = {0.f, 0.f, 0.f, 0.f};
        #pragma unroll
        for (int di = 0; di < 4; ++di) {
            const int kl = wr * 64 + di * 16 + lg * 4;
            const int kg = tk * 128 + kl;
            f32x4 sqk;
            if (mat) sqk = *(const f32x4*)(sqb + kg);
            #pragma unroll
            for (int qi = 0; qi < 4; ++qi) {
                const int qg = tq * 128 + wc * 64 + qi * 16 + l16;
                half4 hv;
                #pragma unroll
                for (int r = 0; r < 4; ++r) {
                    const bool msk = (kg + r) < qg;        // causal + zero-diag
                    float p;
                    if (mat) p = msk ? __expf(-0.5f * (sqq[qi] + sqk[r] - 2.f * acc[di][qi][r])) : 0.f;
                    else     p = msk ? fmaxf(acc[di][qi][r], 0.f) : 0.f;
                    dsum[qi] += p;
                    hv[r] = (_Float16)p;
                }
                *(half4*)(Pt + (size_t)(wc * 64 + qi * 16 + l16) * 128 + kl) = hv;
                acc[di][qi] = (f32x4)0.f;
            }
        }
        #pragma unroll
        for (int qi = 0; qi < 4; ++qi) {
            dsum[qi] += __shfl_xor(dsum[qi], 16);
            dsum[qi] += __shfl_xor(dsum[qi], 32);
        }
        if (lg == 0) {
            #pragma unroll
            for (int qi = 0; qi < 4; ++qi)
                degpart[(size_t)(bm * TRI + tile) * 256 + wr * 128 + wc * 64 + qi * 16 + l16] = dsum[qi];
        }
    };

    STAGE(0, 0);
    STAGE(1, 1);
    BAR_V4();                                  // stage(0) landed; stage(1) in flight

    #pragma unroll
    for (int j = 0; j < 16; ++j) {
        if (j < 14) STAGE((j + 2) % 3, j + 2);
        const int cb = j % 3;
        half8 a[4], bq[4];
        #pragma unroll
        for (int i = 0; i < 4; ++i) {
            a[i]  = ldsfrag(&At[cb][0], wr * 64 + i * 16 + l16, lg);
            bq[i] = ldsfrag(&Bq[cb][0], wc * 64 + i * 16 + l16, lg);
        }
        __builtin_amdgcn_s_setprio(1);
        #pragma unroll
        for (int di = 0; di < 4; ++di)
            #pragma unroll
            for (int qi = 0; qi < 4; ++qi)
                acc[di][qi] = mfma_16x16x32(a[di], bq[qi], acc[di][qi]);
        __builtin_amdgcn_s_setprio(0);
        if (j == 7) EPI(tk0);                  // overlaps tile1 stages in flight
        if (j == 15 && has1) EPI(tk1);
        if (j < 14) BAR_V4();
        else if (j == 14) BAR_V0();
    }
}

// ---------------- PV GEMM (R8-proven): BK=32, tri-buffer, counted vmcnt ----------
__global__ __launch_bounds__(256, 3) void k_pv(const _Float16* __restrict__ P,
                                               const _Float16* __restrict__ vT,
                                               _Float16* __restrict__ part,
                                               int CHUNK, int NCH) {
    const int dh = blockIdx.x & 1, mat = (blockIdx.x >> 1) & 1;
    int x = NCH - 1 - (blockIdx.x >> 2);     // reversed: long chunks dispatch first
    int tq = 0, cum = 0;
    for (;;) {
        const int nc = (tq + CHUNK) / CHUNK;  // ceil((tq+1)/CHUNK)
        if (x < nc) break;
        x -= nc; cum += nc; ++tq;
    }
    const int c = x;
    const int b = blockIdx.y;
    const int kt0 = c * CHUNK;
    const int ktE = (kt0 + CHUNK < tq + 1) ? kt0 + CHUNK : tq + 1;
    const int NS = (ktE - kt0) * 4;          // BK=32 steps

    const int w = threadIdx.x >> 6, lane = threadIdx.x & 63;
    const int l16 = lane & 15, lg = lane >> 4;
    const int wr = w >> 1, wc = w & 1;

    __shared__ char At[3][8192], Bp[3][8192];

    const char* vTb = (const char*)(vT + (size_t)b * ND * NN) + (size_t)dh * 128 * (NN * 2);
    const char* Pbase = (const char*)(P + (size_t)((b * 2 + mat) * TRI + tri32(tq)) * 16384);

    auto STAGE = [&](int bufi, int j_) {
        const int kt = kt0 + (j_ >> 2), sub = j_ & 3;
        stage_side(vTb + (size_t)kt * 256 + sub * 64, (size_t)NN * 2, &At[bufi][0]);
        stage_side(Pbase + (size_t)kt * 32768 + sub * 64, 256, &Bp[bufi][0]);
    };

    f32x4 acc[4][4];
    #pragma unroll
    for (int i = 0; i < 4; ++i)
        #pragma unroll
        for (int j = 0; j < 4; ++j) acc[i][j] = (f32x4)0.f;

    STAGE(0, 0);
    STAGE(1, 1);
    BAR_V4();

    for (int s = 0; s < NS; ++s) {
        if (s + 2 < NS) STAGE((s + 2) % 3, s + 2);
        const int cb = s % 3;
        half8 a[4], bp[4];
        #pragma unroll
        for (int i = 0; i < 4; ++i) {
            a[i]  = ldsfrag(&At[cb][0], wr * 64 + i * 16 + l16, lg);
            bp[i] = ldsfrag(&Bp[cb][0], wc * 64 + i * 16 + l16, lg);
        }
        #pragma unroll
        for (int di = 0; di < 4; ++di)
            #pragma unroll
            for (int qi = 0; qi < 4; ++qi)
                acc[di][qi] = mfma_16x16x32(a[di], bp[qi], acc[di][qi]);
        if (s + 2 < NS) BAR_V4();
        else if (s + 1 < NS) BAR_V0();
    }

    _Float16* sl = part + (size_t)(((b * NCH + cum + c) * 2 + dh) * 2 + mat) * 16384;
    #pragma unroll
    for (int di = 0; di < 4; ++di) {
        const int dl = wr * 64 + di * 16 + lg * 4;
        #pragma unroll
        for (int qi = 0; qi < 4; ++qi) {
            half4 hv;
            #pragma unroll
            for (int r = 0; r < 4; ++r) hv[r] = (_Float16)acc[di][qi][r];
            *(half4*)(sl + (size_t)(wc * 64 + qi * 16 + l16) * 128 + dl) = hv;
        }
    }
}

// ---------------- fused combine + normalize + @Wo -> out ----------------
__global__ __launch_bounds__(512) void k_combo(const _Float16* __restrict__ part,
                                               const float* __restrict__ degpart,
                                               const _Float16* __restrict__ Wot,
                                               float* __restrict__ out,
                                               int CHUNK, int NCH) {
    const int tq = blockIdx.x, b = blockIdx.y;
    __shared__ _Float16 ot_t[128][264];      // 528B rows
    __shared__ float rl[128], rg[128];

    if (threadIdx.x < 256) {
        const int i = threadIdx.x & 127;
        const int m = threadIdx.x >> 7;
        const float* dp = degpart + (size_t)((b * 2 + m) * TRI + tri32(tq)) * 256 + i;
        float d = 0.f;
        for (int tk = 0; tk <= tq; ++tk)
            d += dp[(size_t)tk * 256] + dp[(size_t)tk * 256 + 128];
        (m ? rg : rl)[i] = (m ? 0.1f : 0.9f) / fmaxf(d, 1e-8f);
    }
    __syncthreads();

    int cum = 0;
    for (int t = 0; t < tq; ++t) cum += (t + CHUNK) / CHUNK;
    const int nc = (tq + CHUNK) / CHUNK;
    #pragma unroll
    for (int it = 0; it < 8; ++it) {
        const int f = it * 4096 + threadIdx.x * 8;   // 32768 f16 total
        const int dh = f >> 14, rem = f & 16383;
        const int row = rem >> 7, col = rem & 127;
        float s_l[8] = {0,0,0,0,0,0,0,0}, s_g[8] = {0,0,0,0,0,0,0,0};
        const _Float16* p0 = part + (size_t)(((b * NCH + cum) * 2 + dh) * 2) * 16384 + rem;
        for (int c = 0; c < nc; ++c) {
            half8 xl = *(const half8*)(p0 + (size_t)c * 4 * 16384);
            half8 xg = *(const half8*)(p0 + (size_t)c * 4 * 16384 + 16384);
            #pragma unroll
            for (int k = 0; k < 8; ++k) { s_l[k] += (float)xl[k]; s_g[k] += (float)xg[k]; }
        }
        half8 o;
        #pragma unroll
        for (int k = 0; k < 8; ++k)
            o[k] = (_Float16)(rl[row] * s_l[k] + rg[row] * s_g[k]);
        *(half8*)&ot_t[row][dh * 128 + col] = o;
    }
    __syncthreads();

    const int w = threadIdx.x >> 6, l = threadIdx.x & 63;
    const int l16 = l & 15, lg = l >> 4;
    const int row0 = w * 16;
    f32x4 acc[16];
    #pragma unroll
    for (int i = 0; i < 16; ++i) acc[i] = (f32x4)0.f;
    #pragma unroll
    for (int ks = 0; ks < 8; ++ks) {
        half8 a = *(const half8*)&ot_t[row0 + l16][ks * 32 + lg * 8];
        #pragma unroll
        for (int ct = 0; ct < 16; ++ct) {
            half8 bw = *(const half8*)(Wot + (size_t)(ct * 16 + l16) * ND + ks * 32 + lg * 8);
            acc[ct] = mfma_16x16x32(a, bw, acc[ct]);
        }
    }
    #pragma unroll
    for (int ct = 0; ct < 16; ++ct)
        #pragma unroll
        for (int r = 0; r < 4; ++r)
            out[(size_t)(b * NN + tq * 128 + row0 + lg * 4 + r) * ND + ct * 16 + l16] = acc[ct][r];
}

extern "C" void kernel_launch(void* const* d_in, const int* in_sizes, int n_in,
                              void* d_out, int out_size, void* d_ws, size_t ws_size,
                              hipStream_t stream) {
    const float* h  = (const float*)d_in[0];
    const float* Wl = (const float*)d_in[2];
    const float* Wg = (const float*)d_in[3];
    const float* Wv = (const float*)d_in[4];
    const float* Wo = (const float*)d_in[5];
    float* out = (float*)d_out;

    uint8_t* base = (uint8_t*)d_ws;
    size_t off = 0;
    auto alloc = [&](size_t bytes) -> void* {
        void* r = base + off;
        off = (off + bytes + 255) & ~(size_t)255;
        return r;
    };
    const size_t bnd = (size_t)NB * NN * ND;
    _Float16* h16 = (_Float16*)alloc(bnd * 2);     // reused as vT after k_proj
    _Float16* Wlt = (_Float16*)alloc(ND * ND * 2);
    _Float16* Wgt = (_Float16*)alloc(ND * ND * 2);
    _Float16* Wvt = (_Float16*)alloc(ND * ND * 2);
    _Float16* Wot = (_Float16*)alloc(ND * ND * 2);
    _Float16* zn  = (_Float16*)alloc(bnd * 2);
    _Float16* zg  = (_Float16*)alloc(bnd * 2);
    _Float16* v16 = (_Float16*)alloc(bnd * 2);
    float*    sq  = (float*)alloc((size_t)NB * NN * 4);
    _Float16* P   = (_Float16*)alloc((size_t)NB * 2 * TRI * 16384 * 2);   // 69 MB
    float* degpart = (float*)alloc((size_t)NB * 2 * TRI * 256 * 4);       // 2.2 MB
    _Float16* vT = h16;                            // alias: h16 dead after k_proj

    // split-K chunking with ws fallback
    int CHUNK = 8, NCH = 0;
    for (;;) {
        NCH = 0;
        for (int t = 0; t < 32; ++t) NCH += (t + CHUNK) / CHUNK;
        if (off + (size_t)NB * NCH * 4 * 16384 * 2 + 256 <= ws_size || CHUNK >= 32) break;
        CHUNK *= 2;
    }
    _Float16* part = (_Float16*)alloc((size_t)NB * NCH * 4 * 16384 * 2);

    k_cvt_h<<<bnd / 4 / 256, 256, 0, stream>>>(h, h16);
    k_wt<<<dim3(ND, 4), 256, 0, stream>>>(Wl, Wg, Wv, Wo, Wlt, Wgt, Wvt, Wot);
    k_proj<<<dim3(NB * NN / 64, 3), 256, 0, stream>>>(h16, Wlt, Wgt, Wvt, zn, zg, v16, sq);
    k_tr<<<dim3(NN / 64, ND / 64, NB), 256, 0, stream>>>(v16, vT);
    k_score<<<NB * 2 * NPAIR, 256, 0, stream>>>(zn, zg, sq, P, degpart);
    k_pv<<<dim3(4 * NCH, NB), 256, 0, stream>>>(P, vT, part, CHUNK, NCH);
    k_combo<<<dim3(32, NB), 512, 0, stream>>>(part, degpart, Wot, out, CHUNK, NCH);
}

// Round 13
// 186.557 us; speedup vs baseline: 1.0401x; 1.0362x over previous
//
#include <hip/hip_runtime.h>
#include <cstdint>
#include <cstddef>

#define NB 2
#define NN 4096
#define ND 256
#define TRI 528   // 32*33/2 causal 128-tiles per (batch, mat)

typedef __attribute__((ext_vector_type(8))) _Float16 half8;
typedef __attribute__((ext_vector_type(4))) _Float16 half4;
typedef __attribute__((ext_vector_type(4))) float f32x4;

using gas_ptr = const __attribute__((address_space(1))) void*;
using las_ptr = __attribute__((address_space(3))) void*;

__device__ __host__ __forceinline__ int tri32(int t) { return t * (t + 1) / 2; }

__device__ __forceinline__ f32x4 mfma_16x16x32(half8 a, half8 b, f32x4 c) {
    return __builtin_amdgcn_mfma_f32_16x16x32_f16(a, b, c, 0, 0, 0);
}

#define BAR_V4() asm volatile("s_waitcnt vmcnt(4) lgkmcnt(0)\n\ts_barrier" ::: "memory")
#define BAR_V0() asm volatile("s_waitcnt vmcnt(0) lgkmcnt(0)\n\ts_barrier" ::: "memory")

// ---- 128-row x 64B staging side, paired-row swizzle (2 logical rows / 128B) ----
__device__ __forceinline__ void stage_side(const char* __restrict__ gb, size_t rstride,
                                           char* lb) {
    #pragma unroll
    for (int i = 0; i < 2; ++i) {
        const int o = threadIdx.x * 16 + i * 4096;
        const int rp = o >> 7;
        const int uw = (o & 127) ^ ((rp & 7) << 4);
        const int r = rp * 2 + (uw >> 6);
        const int c = uw & 63;
        __builtin_amdgcn_global_load_lds((gas_ptr)(gb + (size_t)r * rstride + c),
                                         (las_ptr)(lb + o), 16, 0, 0);
    }
}

__device__ __forceinline__ half8 ldsfrag(const char* lb, int row, int lg) {
    const int rp = row >> 1;
    const int x = (((row & 1) << 6) + (lg << 4)) ^ ((rp & 7) << 4);
    return *(const half8*)(lb + rp * 128 + x);
}

// ---------------- conversions ----------------
__global__ __launch_bounds__(256) void k_cvt_h(const float* __restrict__ h,
                                               _Float16* __restrict__ h16) {
    const int i = blockIdx.x * 256 + threadIdx.x;
    f32x4 v = ((const f32x4*)h)[i];
    half4 o;
    o[0] = (_Float16)v[0]; o[1] = (_Float16)v[1];
    o[2] = (_Float16)v[2]; o[3] = (_Float16)v[3];
    ((half4*)h16)[i] = o;
}

__global__ __launch_bounds__(256) void k_wt(const float* __restrict__ W0, const float* __restrict__ W1,
                                            const float* __restrict__ W2, const float* __restrict__ W3,
                                            _Float16* __restrict__ T0, _Float16* __restrict__ T1,
                                            _Float16* __restrict__ T2, _Float16* __restrict__ T3) {
    const int m = blockIdx.y;
    const float* W = m == 0 ? W0 : m == 1 ? W1 : m == 2 ? W2 : W3;
    _Float16* T    = m == 0 ? T0 : m == 1 ? T1 : m == 2 ? T2 : T3;
    const int k = blockIdx.x, j = threadIdx.x;
    T[j * ND + k] = (_Float16)W[k * ND + j];
}

// ---------------- GEMM core (projections) ----------------
__device__ __forceinline__ void gemm_core(const _Float16* __restrict__ A,
                                          const _Float16* __restrict__ Bt,
                                          int row0, int l16, int lg, f32x4 acc[16]) {
    #pragma unroll
    for (int i = 0; i < 16; ++i) acc[i] = (f32x4)0.0f;
    #pragma unroll
    for (int ks = 0; ks < 8; ++ks) {
        half8 a = *(const half8*)(A + (size_t)(row0 + l16) * ND + ks * 32 + lg * 8);
        #pragma unroll
        for (int ct = 0; ct < 16; ++ct) {
            half8 b = *(const half8*)(Bt + (size_t)(ct * 16 + l16) * ND + ks * 32 + lg * 8);
            acc[ct] = mfma_16x16x32(a, b, acc[ct]);
        }
    }
}

__global__ __launch_bounds__(256) void k_proj(const _Float16* __restrict__ h16,
                                              const _Float16* __restrict__ Wlt,
                                              const _Float16* __restrict__ Wgt,
                                              const _Float16* __restrict__ Wvt,
                                              _Float16* __restrict__ zn,
                                              _Float16* __restrict__ zg,
                                              _Float16* __restrict__ v16,
                                              float* __restrict__ sq) {
    const int mode = blockIdx.y;
    const _Float16* Bt = mode == 0 ? Wlt : mode == 1 ? Wgt : Wvt;
    _Float16* o16      = mode == 0 ? zn  : mode == 1 ? zg  : v16;
    const int w = threadIdx.x >> 6, l = threadIdx.x & 63;
    const int l16 = l & 15, lg = l >> 4;
    const int row0 = blockIdx.x * 64 + w * 16;
    f32x4 acc[16];
    gemm_core(h16, Bt, row0, l16, lg, acc);

    if (mode == 2) {
        #pragma unroll
        for (int ct = 0; ct < 16; ++ct)
            #pragma unroll
            for (int r = 0; r < 4; ++r)
                o16[(size_t)(row0 + lg * 4 + r) * ND + ct * 16 + l16] = (_Float16)acc[ct][r];
        return;
    }
    float n2[4] = {0.f, 0.f, 0.f, 0.f};
    #pragma unroll
    for (int ct = 0; ct < 16; ++ct)
        #pragma unroll
        for (int r = 0; r < 4; ++r) n2[r] += acc[ct][r] * acc[ct][r];
    #pragma unroll
    for (int m = 1; m < 16; m <<= 1) {
        #pragma unroll
        for (int r = 0; r < 4; ++r) n2[r] += __shfl_xor(n2[r], m);
    }
    if (mode == 0) {
        float ri[4];
        #pragma unroll
        for (int r = 0; r < 4; ++r) ri[r] = 1.0f / fmaxf(sqrtf(n2[r]), 1e-8f);
        #pragma unroll
        for (int ct = 0; ct < 16; ++ct)
            #pragma unroll
            for (int r = 0; r < 4; ++r)
                o16[(size_t)(row0 + lg * 4 + r) * ND + ct * 16 + l16] =
                    (_Float16)(acc[ct][r] * ri[r]);
    } else {
        #pragma unroll
        for (int ct = 0; ct < 16; ++ct)
            #pragma unroll
            for (int r = 0; r < 4; ++r)
                o16[(size_t)(row0 + lg * 4 + r) * ND + ct * 16 + l16] = (_Float16)acc[ct][r];
        if (l16 == 0) {
            #pragma unroll
            for (int r = 0; r < 4; ++r) sq[row0 + lg * 4 + r] = n2[r];
        }
    }
}

// v16 [b][n][d] -> vT [b][d][n]
__global__ __launch_bounds__(256) void k_tr(const _Float16* __restrict__ v16,
                                            _Float16* __restrict__ vT) {
    __shared__ _Float16 t[64][72];
    const int b = blockIdx.z, n0 = blockIdx.x * 64, d0 = blockIdx.y * 64;
    const int tj = threadIdx.x & 63, ti = threadIdx.x >> 6;
    #pragma unroll
    for (int i = 0; i < 16; ++i)
        t[ti + i * 4][tj] = v16[(size_t)(b * NN + n0 + ti + i * 4) * ND + d0 + tj];
    __syncthreads();
    #pragma unroll
    for (int i = 0; i < 16; ++i)
        vT[(size_t)(b * ND + d0 + ti + i * 4) * NN + n0 + tj] = t[tj][ti + i * 4];
}

// ---------------- score GEMM (R11-proven): 1 tile/block + XCD swizzle + setprio --
// One 128-tile per block, BK=32, tri-buffer, counted vmcnt(4). Grid 2112 flat.
__global__ __launch_bounds__(256, 3) void k_score(const _Float16* __restrict__ zn,
                                                  const _Float16* __restrict__ zg,
                                                  const float* __restrict__ sqg,
                                                  _Float16* __restrict__ P,
                                                  float* __restrict__ degpart) {
    const int orig = blockIdx.x;
    const int wgid = (orig & 7) * (NB * 2 * TRI / 8) + (orig >> 3);  // bijective XCD swizzle
    const int bm = wgid / TRI;
    int x = wgid % TRI, tq = 0;
    while (x > tq) { x -= (tq + 1); ++tq; }
    const int tk = x;
    const int b = bm >> 1, mat = bm & 1;
    const char* z = (const char*)((mat ? zg : zn) + (size_t)b * NN * ND);
    const float* sqb = sqg + (size_t)b * NN;
    const int w = threadIdx.x >> 6, lane = threadIdx.x & 63;
    const int l16 = lane & 15, lg = lane >> 4;
    const int wr = w >> 1, wc = w & 1;

    __shared__ char At[3][8192], Bq[3][8192];

    const char* zk = z + (size_t)tk * 128 * 512;
    const char* zq = z + (size_t)tq * 128 * 512;

    auto STAGE = [&](int bufi, int s_) {
        stage_side(zk + s_ * 64, 512, &At[bufi][0]);
        stage_side(zq + s_ * 64, 512, &Bq[bufi][0]);
    };

    f32x4 acc[4][4];
    #pragma unroll
    for (int i = 0; i < 4; ++i)
        #pragma unroll
        for (int j = 0; j < 4; ++j) acc[i][j] = (f32x4)0.f;

    STAGE(0, 0);
    STAGE(1, 1);
    BAR_V4();                                  // stage(0) landed; stage(1) in flight

    #pragma unroll
    for (int s = 0; s < 8; ++s) {
        if (s < 6) STAGE((s + 2) % 3, s + 2);
        const int cb = s % 3;
        half8 a[4], bq[4];
        #pragma unroll
        for (int i = 0; i < 4; ++i) {
            a[i]  = ldsfrag(&At[cb][0], wr * 64 + i * 16 + l16, lg);
            bq[i] = ldsfrag(&Bq[cb][0], wc * 64 + i * 16 + l16, lg);
        }
        __builtin_amdgcn_s_setprio(1);
        #pragma unroll
        for (int di = 0; di < 4; ++di)
            #pragma unroll
            for (int qi = 0; qi < 4; ++qi)
                acc[di][qi] = mfma_16x16x32(a[di], bq[qi], acc[di][qi]);
        __builtin_amdgcn_s_setprio(0);
        if (s < 6) BAR_V4();
        else if (s == 6) BAR_V0();
    }

    // ---- epilogue: transform, P write, degree partials
    const int tile = tri32(tq) + tk;
    _Float16* Pt = P + (size_t)(bm * TRI + tile) * 16384;
    float dsum[4] = {0.f, 0.f, 0.f, 0.f};
    float sqq[4];
    if (mat) {
        #pragma unroll
        for (int qi = 0; qi < 4; ++qi)
            sqq[qi] = sqb[tq * 128 + wc * 64 + qi * 16 + l16];
    }
    #pragma unroll
    for (int di = 0; di < 4; ++di) {
        const int kl = wr * 64 + di * 16 + lg * 4;
        const int kg = tk * 128 + kl;
        f32x4 sqk;
        if (mat) sqk = *(const f32x4*)(sqb + kg);
        #pragma unroll
        for (int qi = 0; qi < 4; ++qi) {
            const int qg = tq * 128 + wc * 64 + qi * 16 + l16;
            half4 hv;
            #pragma unroll
            for (int r = 0; r < 4; ++r) {
                const bool msk = (kg + r) < qg;        // causal + zero-diag
                float p;
                if (mat) p = msk ? __expf(-0.5f * (sqq[qi] + sqk[r] - 2.f * acc[di][qi][r])) : 0.f;
                else     p = msk ? fmaxf(acc[di][qi][r], 0.f) : 0.f;
                dsum[qi] += p;
                hv[r] = (_Float16)p;
            }
            *(half4*)(Pt + (size_t)(wc * 64 + qi * 16 + l16) * 128 + kl) = hv;
        }
    }
    #pragma unroll
    for (int qi = 0; qi < 4; ++qi) {
        dsum[qi] += __shfl_xor(dsum[qi], 16);
        dsum[qi] += __shfl_xor(dsum[qi], 32);
    }
    if (lg == 0) {
        #pragma unroll
        for (int qi = 0; qi < 4; ++qi)
            degpart[(size_t)(bm * TRI + tile) * 256 + wr * 128 + wc * 64 + qi * 16 + l16] = dsum[qi];
    }
}

// ---------------- PV GEMM (R8-proven): BK=32, tri-buffer, counted vmcnt ----------
__global__ __launch_bounds__(256, 3) void k_pv(const _Float16* __restrict__ P,
                                               const _Float16* __restrict__ vT,
                                               _Float16* __restrict__ part,
                                               int CHUNK, int NCH) {
    const int dh = blockIdx.x & 1, mat = (blockIdx.x >> 1) & 1;
    int x = NCH - 1 - (blockIdx.x >> 2);     // reversed: long chunks dispatch first
    int tq = 0, cum = 0;
    for (;;) {
        const int nc = (tq + CHUNK) / CHUNK;  // ceil((tq+1)/CHUNK)
        if (x < nc) break;
        x -= nc; cum += nc; ++tq;
    }
    const int c = x;
    const int b = blockIdx.y;
    const int kt0 = c * CHUNK;
    const int ktE = (kt0 + CHUNK < tq + 1) ? kt0 + CHUNK : tq + 1;
    const int NS = (ktE - kt0) * 4;          // BK=32 steps

    const int w = threadIdx.x >> 6, lane = threadIdx.x & 63;
    const int l16 = lane & 15, lg = lane >> 4;
    const int wr = w >> 1, wc = w & 1;

    __shared__ char At[3][8192], Bp[3][8192];

    const char* vTb = (const char*)(vT + (size_t)b * ND * NN) + (size_t)dh * 128 * (NN * 2);
    const char* Pbase = (const char*)(P + (size_t)((b * 2 + mat) * TRI + tri32(tq)) * 16384);

    auto STAGE = [&](int bufi, int j_) {
        const int kt = kt0 + (j_ >> 2), sub = j_ & 3;
        stage_side(vTb + (size_t)kt * 256 + sub * 64, (size_t)NN * 2, &At[bufi][0]);
        stage_side(Pbase + (size_t)kt * 32768 + sub * 64, 256, &Bp[bufi][0]);
    };

    f32x4 acc[4][4];
    #pragma unroll
    for (int i = 0; i < 4; ++i)
        #pragma unroll
        for (int j = 0; j < 4; ++j) acc[i][j] = (f32x4)0.f;

    STAGE(0, 0);
    STAGE(1, 1);
    BAR_V4();

    for (int s = 0; s < NS; ++s) {
        if (s + 2 < NS) STAGE((s + 2) % 3, s + 2);
        const int cb = s % 3;
        half8 a[4], bp[4];
        #pragma unroll
        for (int i = 0; i < 4; ++i) {
            a[i]  = ldsfrag(&At[cb][0], wr * 64 + i * 16 + l16, lg);
            bp[i] = ldsfrag(&Bp[cb][0], wc * 64 + i * 16 + l16, lg);
        }
        #pragma unroll
        for (int di = 0; di < 4; ++di)
            #pragma unroll
            for (int qi = 0; qi < 4; ++qi)
                acc[di][qi] = mfma_16x16x32(a[di], bp[qi], acc[di][qi]);
        if (s + 2 < NS) BAR_V4();
        else if (s + 1 < NS) BAR_V0();
    }

    _Float16* sl = part + (size_t)(((b * NCH + cum + c) * 2 + dh) * 2 + mat) * 16384;
    #pragma unroll
    for (int di = 0; di < 4; ++di) {
        const int dl = wr * 64 + di * 16 + lg * 4;
        #pragma unroll
        for (int qi = 0; qi < 4; ++qi) {
            half4 hv;
            #pragma unroll
            for (int r = 0; r < 4; ++r) hv[r] = (_Float16)acc[di][qi][r];
            *(half4*)(sl + (size_t)(wc * 64 + qi * 16 + l16) * 128 + dl) = hv;
        }
    }
}

// ---------------- fused combine + normalize + @Wo -> out ----------------
__global__ __launch_bounds__(512) void k_combo(const _Float16* __restrict__ part,
                                               const float* __restrict__ degpart,
                                               const _Float16* __restrict__ Wot,
                                               float* __restrict__ out,
                                               int CHUNK, int NCH) {
    const int tq = blockIdx.x, b = blockIdx.y;
    __shared__ _Float16 ot_t[128][264];      // 528B rows
    __shared__ float rl[128], rg[128];

    if (threadIdx.x < 256) {
        const int i = threadIdx.x & 127;
        const int m = threadIdx.x >> 7;
        const float* dp = degpart + (size_t)((b * 2 + m) * TRI + tri32(tq)) * 256 + i;
        float d = 0.f;
        for (int tk = 0; tk <= tq; ++tk)
            d += dp[(size_t)tk * 256] + dp[(size_t)tk * 256 + 128];
        (m ? rg : rl)[i] = (m ? 0.1f : 0.9f) / fmaxf(d, 1e-8f);
    }
    __syncthreads();

    int cum = 0;
    for (int t = 0; t < tq; ++t) cum += (t + CHUNK) / CHUNK;
    const int nc = (tq + CHUNK) / CHUNK;
    #pragma unroll
    for (int it = 0; it < 8; ++it) {
        const int f = it * 4096 + threadIdx.x * 8;   // 32768 f16 total
        const int dh = f >> 14, rem = f & 16383;
        const int row = rem >> 7, col = rem & 127;
        float s_l[8] = {0,0,0,0,0,0,0,0}, s_g[8] = {0,0,0,0,0,0,0,0};
        const _Float16* p0 = part + (size_t)(((b * NCH + cum) * 2 + dh) * 2) * 16384 + rem;
        for (int c = 0; c < nc; ++c) {
            half8 xl = *(const half8*)(p0 + (size_t)c * 4 * 16384);
            half8 xg = *(const half8*)(p0 + (size_t)c * 4 * 16384 + 16384);
            #pragma unroll
            for (int k = 0; k < 8; ++k) { s_l[k] += (float)xl[k]; s_g[k] += (float)xg[k]; }
        }
        half8 o;
        #pragma unroll
        for (int k = 0; k < 8; ++k)
            o[k] = (_Float16)(rl[row] * s_l[k] + rg[row] * s_g[k]);
        *(half8*)&ot_t[row][dh * 128 + col] = o;
    }
    __syncthreads();

    const int w = threadIdx.x >> 6, l = threadIdx.x & 63;
    const int l16 = l & 15, lg = l >> 4;
    const int row0 = w * 16;
    f32x4 acc[16];
    #pragma unroll
    for (int i = 0; i < 16; ++i) acc[i] = (f32x4)0.f;
    #pragma unroll
    for (int ks = 0; ks < 8; ++ks) {
        half8 a = *(const half8*)&ot_t[row0 + l16][ks * 32 + lg * 8];
        #pragma unroll
        for (int ct = 0; ct < 16; ++ct) {
            half8 bw = *(const half8*)(Wot + (size_t)(ct * 16 + l16) * ND + ks * 32 + lg * 8);
            acc[ct] = mfma_16x16x32(a, bw, acc[ct]);
        }
    }
    #pragma unroll
    for (int ct = 0; ct < 16; ++ct)
        #pragma unroll
        for (int r = 0; r < 4; ++r)
            out[(size_t)(b * NN + tq * 128 + row0 + lg * 4 + r) * ND + ct * 16 + l16] = acc[ct][r];
}

extern "C" void kernel_launch(void* const* d_in, const int* in_sizes, int n_in,
                              void* d_out, int out_size, void* d_ws, size_t ws_size,
                              hipStream_t stream) {
    const float* h  = (const float*)d_in[0];
    const float* Wl = (const float*)d_in[2];
    const float* Wg = (const float*)d_in[3];
    const float* Wv = (const float*)d_in[4];
    const float* Wo = (const float*)d_in[5];
    float* out = (float*)d_out;

    uint8_t* base = (uint8_t*)d_ws;
    size_t off = 0;
    auto alloc = [&](size_t bytes) -> void* {
        void* r = base + off;
        off = (off + bytes + 255) & ~(size_t)255;
        return r;
    };
    const size_t bnd = (size_t)NB * NN * ND;
    _Float16* h16 = (_Float16*)alloc(bnd * 2);     // reused as vT after k_proj
    _Float16* Wlt = (_Float16*)alloc(ND * ND * 2);
    _Float16* Wgt = (_Float16*)alloc(ND * ND * 2);
    _Float16* Wvt = (_Float16*)alloc(ND * ND * 2);
    _Float16* Wot = (_Float16*)alloc(ND * ND * 2);
    _Float16* zn  = (_Float16*)alloc(bnd * 2);
    _Float16* zg  = (_Float16*)alloc(bnd * 2);
    _Float16* v16 = (_Float16*)alloc(bnd * 2);
    float*    sq  = (float*)alloc((size_t)NB * NN * 4);
    _Float16* P   = (_Float16*)alloc((size_t)NB * 2 * TRI * 16384 * 2);   // 69 MB
    float* degpart = (float*)alloc((size_t)NB * 2 * TRI * 256 * 4);       // 2.2 MB
    _Float16* vT = h16;                            // alias: h16 dead after k_proj

    // split-K chunking with ws fallback
    int CHUNK = 8, NCH = 0;
    for (;;) {
        NCH = 0;
        for (int t = 0; t < 32; ++t) NCH += (t + CHUNK) / CHUNK;
        if (off + (size_t)NB * NCH * 4 * 16384 * 2 + 256 <= ws_size || CHUNK >= 32) break;
        CHUNK *= 2;
    }
    _Float16* part = (_Float16*)alloc((size_t)NB * NCH * 4 * 16384 * 2);

    k_cvt_h<<<bnd / 4 / 256, 256, 0, stream>>>(h, h16);
    k_wt<<<dim3(ND, 4), 256, 0, stream>>>(Wl, Wg, Wv, Wo, Wlt, Wgt, Wvt, Wot);
    k_proj<<<dim3(NB * NN / 64, 3), 256, 0, stream>>>(h16, Wlt, Wgt, Wvt, zn, zg, v16, sq);
    k_tr<<<dim3(NN / 64, ND / 64, NB), 256, 0, stream>>>(v16, vT);
    k_score<<<NB * 2 * TRI, 256, 0, stream>>>(zn, zg, sq, P, degpart);
    k_pv<<<dim3(4 * NCH, NB), 256, 0, stream>>>(P, vT, part, CHUNK, NCH);
    k_combo<<<dim3(32, NB), 512, 0, stream>>>(part, degpart, Wot, out, CHUNK, NCH);
}

// Round 14
// 174.393 us; speedup vs baseline: 1.1126x; 1.0698x over previous
//
#include <hip/hip_runtime.h>
#include <cstdint>
#include <cstddef>

#define NB 2
#define NN 4096
#define ND 256
#define TRI 528   // 32*33/2 causal 128-tiles per (batch, mat)

typedef __attribute__((ext_vector_type(8))) _Float16 half8;
typedef __attribute__((ext_vector_type(4))) _Float16 half4;
typedef __attribute__((ext_vector_type(4))) float f32x4;

using gas_ptr = const __attribute__((address_space(1))) void*;
using las_ptr = __attribute__((address_space(3))) void*;

__device__ __host__ __forceinline__ int tri32(int t) { return t * (t + 1) / 2; }

__device__ __forceinline__ f32x4 mfma_16x16x32(half8 a, half8 b, f32x4 c) {
    return __builtin_amdgcn_mfma_f32_16x16x32_f16(a, b, c, 0, 0, 0);
}

#define BAR_V4() asm volatile("s_waitcnt vmcnt(4) lgkmcnt(0)\n\ts_barrier" ::: "memory")
#define BAR_V0() asm volatile("s_waitcnt vmcnt(0) lgkmcnt(0)\n\ts_barrier" ::: "memory")

// ---- 128-row x 64B staging side, paired-row swizzle (2 logical rows / 128B) ----
__device__ __forceinline__ void stage_side(const char* __restrict__ gb, size_t rstride,
                                           char* lb) {
    #pragma unroll
    for (int i = 0; i < 2; ++i) {
        const int o = threadIdx.x * 16 + i * 4096;
        const int rp = o >> 7;
        const int uw = (o & 127) ^ ((rp & 7) << 4);
        const int r = rp * 2 + (uw >> 6);
        const int c = uw & 63;
        __builtin_amdgcn_global_load_lds((gas_ptr)(gb + (size_t)r * rstride + c),
                                         (las_ptr)(lb + o), 16, 0, 0);
    }
}

__device__ __forceinline__ half8 ldsfrag(const char* lb, int row, int lg) {
    const int rp = row >> 1;
    const int x = (((row & 1) << 6) + (lg << 4)) ^ ((rp & 7) << 4);
    return *(const half8*)(lb + rp * 128 + x);
}

// ---------------- conversions ----------------
__global__ __launch_bounds__(256) void k_cvt_h(const float* __restrict__ h,
                                               _Float16* __restrict__ h16) {
    const int i = blockIdx.x * 256 + threadIdx.x;
    f32x4 v = ((const f32x4*)h)[i];
    half4 o;
    o[0] = (_Float16)v[0]; o[1] = (_Float16)v[1];
    o[2] = (_Float16)v[2]; o[3] = (_Float16)v[3];
    ((half4*)h16)[i] = o;
}

__global__ __launch_bounds__(256) void k_wt(const float* __restrict__ W0, const float* __restrict__ W1,
                                            const float* __restrict__ W2, const float* __restrict__ W3,
                                            _Float16* __restrict__ T0, _Float16* __restrict__ T1,
                                            _Float16* __restrict__ T2, _Float16* __restrict__ T3) {
    const int m = blockIdx.y;
    const float* W = m == 0 ? W0 : m == 1 ? W1 : m == 2 ? W2 : W3;
    _Float16* T    = m == 0 ? T0 : m == 1 ? T1 : m == 2 ? T2 : T3;
    const int k = blockIdx.x, j = threadIdx.x;
    T[j * ND + k] = (_Float16)W[k * ND + j];
}

// ---------------- GEMM core (projections) ----------------
__device__ __forceinline__ void gemm_core(const _Float16* __restrict__ A,
                                          const _Float16* __restrict__ Bt,
                                          int row0, int l16, int lg, f32x4 acc[16]) {
    #pragma unroll
    for (int i = 0; i < 16; ++i) acc[i] = (f32x4)0.0f;
    #pragma unroll
    for (int ks = 0; ks < 8; ++ks) {
        half8 a = *(const half8*)(A + (size_t)(row0 + l16) * ND + ks * 32 + lg * 8);
        #pragma unroll
        for (int ct = 0; ct < 16; ++ct) {
            half8 b = *(const half8*)(Bt + (size_t)(ct * 16 + l16) * ND + ks * 32 + lg * 8);
            acc[ct] = mfma_16x16x32(a, b, acc[ct]);
        }
    }
}

__global__ __launch_bounds__(256) void k_proj(const _Float16* __restrict__ h16,
                                              const _Float16* __restrict__ Wlt,
                                              const _Float16* __restrict__ Wgt,
                                              const _Float16* __restrict__ Wvt,
                                              _Float16* __restrict__ zn,
                                              _Float16* __restrict__ zg,
                                              _Float16* __restrict__ v16,
                                              float* __restrict__ sq) {
    const int mode = blockIdx.y;
    const _Float16* Bt = mode == 0 ? Wlt : mode == 1 ? Wgt : Wvt;
    _Float16* o16      = mode == 0 ? zn  : mode == 1 ? zg  : v16;
    const int w = threadIdx.x >> 6, l = threadIdx.x & 63;
    const int l16 = l & 15, lg = l >> 4;
    const int row0 = blockIdx.x * 64 + w * 16;
    f32x4 acc[16];
    gemm_core(h16, Bt, row0, l16, lg, acc);

    if (mode == 2) {
        #pragma unroll
        for (int ct = 0; ct < 16; ++ct)
            #pragma unroll
            for (int r = 0; r < 4; ++r)
                o16[(size_t)(row0 + lg * 4 + r) * ND + ct * 16 + l16] = (_Float16)acc[ct][r];
        return;
    }
    float n2[4] = {0.f, 0.f, 0.f, 0.f};
    #pragma unroll
    for (int ct = 0; ct < 16; ++ct)
        #pragma unroll
        for (int r = 0; r < 4; ++r) n2[r] += acc[ct][r] * acc[ct][r];
    #pragma unroll
    for (int m = 1; m < 16; m <<= 1) {
        #pragma unroll
        for (int r = 0; r < 4; ++r) n2[r] += __shfl_xor(n2[r], m);
    }
    if (mode == 0) {
        float ri[4];
        #pragma unroll
        for (int r = 0; r < 4; ++r) ri[r] = 1.0f / fmaxf(sqrtf(n2[r]), 1e-8f);
        #pragma unroll
        for (int ct = 0; ct < 16; ++ct)
            #pragma unroll
            for (int r = 0; r < 4; ++r)
                o16[(size_t)(row0 + lg * 4 + r) * ND + ct * 16 + l16] =
                    (_Float16)(acc[ct][r] * ri[r]);
    } else {
        #pragma unroll
        for (int ct = 0; ct < 16; ++ct)
            #pragma unroll
            for (int r = 0; r < 4; ++r)
                o16[(size_t)(row0 + lg * 4 + r) * ND + ct * 16 + l16] = (_Float16)acc[ct][r];
        if (l16 == 0) {
            #pragma unroll
            for (int r = 0; r < 4; ++r) sq[row0 + lg * 4 + r] = n2[r];
        }
    }
}

// v16 [b][n][d] -> vT [b][d][n]
__global__ __launch_bounds__(256) void k_tr(const _Float16* __restrict__ v16,
                                            _Float16* __restrict__ vT) {
    __shared__ _Float16 t[64][72];
    const int b = blockIdx.z, n0 = blockIdx.x * 64, d0 = blockIdx.y * 64;
    const int tj = threadIdx.x & 63, ti = threadIdx.x >> 6;
    #pragma unroll
    for (int i = 0; i < 16; ++i)
        t[ti + i * 4][tj] = v16[(size_t)(b * NN + n0 + ti + i * 4) * ND + d0 + tj];
    __syncthreads();
    #pragma unroll
    for (int i = 0; i < 16; ++i)
        vT[(size_t)(b * ND + d0 + ti + i * 4) * NN + n0 + tj] = t[tj][ti + i * 4];
}

// ---------------- score GEMM: R13 loop + LDS-transposed coalesced P store --------
__global__ __launch_bounds__(256, 3) void k_score(const _Float16* __restrict__ zn,
                                                  const _Float16* __restrict__ zg,
                                                  const float* __restrict__ sqg,
                                                  _Float16* __restrict__ P,
                                                  float* __restrict__ degpart) {
    const int orig = blockIdx.x;
    const int wgid = (orig & 7) * (NB * 2 * TRI / 8) + (orig >> 3);  // bijective XCD swizzle
    const int bm = wgid / TRI;
    int x = wgid % TRI, tq = 0;
    while (x > tq) { x -= (tq + 1); ++tq; }
    const int tk = x;
    const int b = bm >> 1, mat = bm & 1;
    const char* z = (const char*)((mat ? zg : zn) + (size_t)b * NN * ND);
    const float* sqb = sqg + (size_t)b * NN;
    const int w = threadIdx.x >> 6, lane = threadIdx.x & 63;
    const int l16 = lane & 15, lg = lane >> 4;
    const int wr = w >> 1, wc = w & 1;

    __shared__ char smem[49152];             // At[3][8192] | Bq[3][8192]; epilogue tile aliases
    char* At = smem;
    char* Bq = smem + 24576;

    const char* zk = z + (size_t)tk * 128 * 512;
    const char* zq = z + (size_t)tq * 128 * 512;

    auto STAGE = [&](int bufi, int s_) {
        stage_side(zk + s_ * 64, 512, At + bufi * 8192);
        stage_side(zq + s_ * 64, 512, Bq + bufi * 8192);
    };

    f32x4 acc[4][4];
    #pragma unroll
    for (int i = 0; i < 4; ++i)
        #pragma unroll
        for (int j = 0; j < 4; ++j) acc[i][j] = (f32x4)0.f;

    STAGE(0, 0);
    STAGE(1, 1);
    BAR_V4();                                  // stage(0) landed; stage(1) in flight

    #pragma unroll
    for (int s = 0; s < 8; ++s) {
        if (s < 6) STAGE((s + 2) % 3, s + 2);
        const int cb = s % 3;
        half8 a[4], bq[4];
        #pragma unroll
        for (int i = 0; i < 4; ++i) {
            a[i]  = ldsfrag(At + cb * 8192, wr * 64 + i * 16 + l16, lg);
            bq[i] = ldsfrag(Bq + cb * 8192, wc * 64 + i * 16 + l16, lg);
        }
        __builtin_amdgcn_s_setprio(1);
        #pragma unroll
        for (int di = 0; di < 4; ++di)
            #pragma unroll
            for (int qi = 0; qi < 4; ++qi)
                acc[di][qi] = mfma_16x16x32(a[di], bq[qi], acc[di][qi]);
        __builtin_amdgcn_s_setprio(0);
        if (s < 6) BAR_V4();
        else if (s == 6) BAR_V0();
    }

    // ---- epilogue: transform -> LDS (264B-stride tile), degree partials
    const int tile = tri32(tq) + tk;
    float dsum[4] = {0.f, 0.f, 0.f, 0.f};
    float sqq[4];
    if (mat) {
        #pragma unroll
        for (int qi = 0; qi < 4; ++qi)
            sqq[qi] = sqb[tq * 128 + wc * 64 + qi * 16 + l16];
    }
    __syncthreads();                           // compute LDS dead in all waves
    #pragma unroll
    for (int di = 0; di < 4; ++di) {
        const int kl = wr * 64 + di * 16 + lg * 4;
        const int kg = tk * 128 + kl;
        f32x4 sqk;
        if (mat) sqk = *(const f32x4*)(sqb + kg);
        #pragma unroll
        for (int qi = 0; qi < 4; ++qi) {
            const int qloc = wc * 64 + qi * 16 + l16;
            const int qg = tq * 128 + qloc;
            half4 hv;
            #pragma unroll
            for (int r = 0; r < 4; ++r) {
                const bool msk = (kg + r) < qg;        // causal + zero-diag
                float p;
                if (mat) p = msk ? __expf(-0.5f * (sqq[qi] + sqk[r] - 2.f * acc[di][qi][r])) : 0.f;
                else     p = msk ? fmaxf(acc[di][qi][r], 0.f) : 0.f;
                dsum[qi] += p;
                hv[r] = (_Float16)p;
            }
            *(half4*)(smem + qloc * 264 + kl * 2) = hv;
        }
    }
    #pragma unroll
    for (int qi = 0; qi < 4; ++qi) {
        dsum[qi] += __shfl_xor(dsum[qi], 16);
        dsum[qi] += __shfl_xor(dsum[qi], 32);
    }
    if (lg == 0) {
        #pragma unroll
        for (int qi = 0; qi < 4; ++qi)
            degpart[(size_t)(bm * TRI + tile) * 256 + wr * 128 + wc * 64 + qi * 16 + l16] = dsum[qi];
    }
    __syncthreads();
    // ---- coalesced P store: 256 thr x 16B x 8 iters = 32KB tile
    _Float16* Pt = P + (size_t)(bm * TRI + tile) * 16384;
    #pragma unroll
    for (int i = 0; i < 8; ++i) {
        const int o = threadIdx.x * 16 + i * 4096;
        const int row = o >> 8, col = o & 255;
        *(half8*)((char*)Pt + o) = *(const half8*)(smem + row * 264 + col);
    }
}

// ---------------- PV GEMM: R13 loop + LDS-transposed coalesced partial store -----
__global__ __launch_bounds__(256, 3) void k_pv(const _Float16* __restrict__ P,
                                               const _Float16* __restrict__ vT,
                                               _Float16* __restrict__ part,
                                               int CHUNK, int NCH) {
    const int dh = blockIdx.x & 1, mat = (blockIdx.x >> 1) & 1;
    int x = NCH - 1 - (blockIdx.x >> 2);     // reversed: long chunks dispatch first
    int tq = 0, cum = 0;
    for (;;) {
        const int nc = (tq + CHUNK) / CHUNK;  // ceil((tq+1)/CHUNK)
        if (x < nc) break;
        x -= nc; cum += nc; ++tq;
    }
    const int c = x;
    const int b = blockIdx.y;
    const int kt0 = c * CHUNK;
    const int ktE = (kt0 + CHUNK < tq + 1) ? kt0 + CHUNK : tq + 1;
    const int NS = (ktE - kt0) * 4;          // BK=32 steps

    const int w = threadIdx.x >> 6, lane = threadIdx.x & 63;
    const int l16 = lane & 15, lg = lane >> 4;
    const int wr = w >> 1, wc = w & 1;

    __shared__ char smem[49152];             // At[3] | Bp[3]; epilogue tile aliases
    char* At = smem;
    char* Bp = smem + 24576;

    const char* vTb = (const char*)(vT + (size_t)b * ND * NN) + (size_t)dh * 128 * (NN * 2);
    const char* Pbase = (const char*)(P + (size_t)((b * 2 + mat) * TRI + tri32(tq)) * 16384);

    auto STAGE = [&](int bufi, int j_) {
        const int kt = kt0 + (j_ >> 2), sub = j_ & 3;
        stage_side(vTb + (size_t)kt * 256 + sub * 64, (size_t)NN * 2, At + bufi * 8192);
        stage_side(Pbase + (size_t)kt * 32768 + sub * 64, 256, Bp + bufi * 8192);
    };

    f32x4 acc[4][4];
    #pragma unroll
    for (int i = 0; i < 4; ++i)
        #pragma unroll
        for (int j = 0; j < 4; ++j) acc[i][j] = (f32x4)0.f;

    STAGE(0, 0);
    STAGE(1, 1);
    BAR_V4();

    for (int s = 0; s < NS; ++s) {
        if (s + 2 < NS) STAGE((s + 2) % 3, s + 2);
        const int cb = s % 3;
        half8 a[4], bp[4];
        #pragma unroll
        for (int i = 0; i < 4; ++i) {
            a[i]  = ldsfrag(At + cb * 8192, wr * 64 + i * 16 + l16, lg);
            bp[i] = ldsfrag(Bp + cb * 8192, wc * 64 + i * 16 + l16, lg);
        }
        #pragma unroll
        for (int di = 0; di < 4; ++di)
            #pragma unroll
            for (int qi = 0; qi < 4; ++qi)
                acc[di][qi] = mfma_16x16x32(a[di], bp[qi], acc[di][qi]);
        if (s + 2 < NS) BAR_V4();
        else if (s + 1 < NS) BAR_V0();
    }

    __syncthreads();                           // all waves done reading compute LDS
    #pragma unroll
    for (int di = 0; di < 4; ++di) {
        const int dl = wr * 64 + di * 16 + lg * 4;
        #pragma unroll
        for (int qi = 0; qi < 4; ++qi) {
            const int qloc = wc * 64 + qi * 16 + l16;
            half4 hv;
            #pragma unroll
            for (int r = 0; r < 4; ++r) hv[r] = (_Float16)acc[di][qi][r];
            *(half4*)(smem + qloc * 264 + dl * 2) = hv;
        }
    }
    __syncthreads();
    _Float16* sl = part + (size_t)(((b * NCH + cum + c) * 2 + dh) * 2 + mat) * 16384;
    #pragma unroll
    for (int i = 0; i < 8; ++i) {
        const int o = threadIdx.x * 16 + i * 4096;
        const int row = o >> 8, col = o & 255;
        *(half8*)((char*)sl + o) = *(const half8*)(smem + row * 264 + col);
    }
}

// ---------------- fused combine + normalize + @Wo -> out ----------------
__global__ __launch_bounds__(512) void k_combo(const _Float16* __restrict__ part,
                                               const float* __restrict__ degpart,
                                               const _Float16* __restrict__ Wot,
                                               float* __restrict__ out,
                                               int CHUNK, int NCH) {
    const int tq = blockIdx.x, b = blockIdx.y;
    __shared__ _Float16 ot_t[128][264];      // 528B rows
    __shared__ float rl[128], rg[128];

    if (threadIdx.x < 256) {
        const int i = threadIdx.x & 127;
        const int m = threadIdx.x >> 7;
        const float* dp = degpart + (size_t)((b * 2 + m) * TRI + tri32(tq)) * 256 + i;
        float d = 0.f;
        for (int tk = 0; tk <= tq; ++tk)
            d += dp[(size_t)tk * 256] + dp[(size_t)tk * 256 + 128];
        (m ? rg : rl)[i] = (m ? 0.1f : 0.9f) / fmaxf(d, 1e-8f);
    }
    __syncthreads();

    int cum = 0;
    for (int t = 0; t < tq; ++t) cum += (t + CHUNK) / CHUNK;
    const int nc = (tq + CHUNK) / CHUNK;
    #pragma unroll
    for (int it = 0; it < 8; ++it) {
        const int f = it * 4096 + threadIdx.x * 8;   // 32768 f16 total
        const int dh = f >> 14, rem = f & 16383;
        const int row = rem >> 7, col = rem & 127;
        float s_l[8] = {0,0,0,0,0,0,0,0}, s_g[8] = {0,0,0,0,0,0,0,0};
        const _Float16* p0 = part + (size_t)(((b * NCH + cum) * 2 + dh) * 2) * 16384 + rem;
        for (int c = 0; c < nc; ++c) {
            half8 xl = *(const half8*)(p0 + (size_t)c * 4 * 16384);
            half8 xg = *(const half8*)(p0 + (size_t)c * 4 * 16384 + 16384);
            #pragma unroll
            for (int k = 0; k < 8; ++k) { s_l[k] += (float)xl[k]; s_g[k] += (float)xg[k]; }
        }
        half8 o;
        #pragma unroll
        for (int k = 0; k < 8; ++k)
            o[k] = (_Float16)(rl[row] * s_l[k] + rg[row] * s_g[k]);
        *(half8*)&ot_t[row][dh * 128 + col] = o;
    }
    __syncthreads();

    const int w = threadIdx.x >> 6, l = threadIdx.x & 63;
    const int l16 = l & 15, lg = l >> 4;
    const int row0 = w * 16;
    f32x4 acc[16];
    #pragma unroll
    for (int i = 0; i < 16; ++i) acc[i] = (f32x4)0.f;
    #pragma unroll
    for (int ks = 0; ks < 8; ++ks) {
        half8 a = *(const half8*)&ot_t[row0 + l16][ks * 32 + lg * 8];
        #pragma unroll
        for (int ct = 0; ct < 16; ++ct) {
            half8 bw = *(const half8*)(Wot + (size_t)(ct * 16 + l16) * ND + ks * 32 + lg * 8);
            acc[ct] = mfma_16x16x32(a, bw, acc[ct]);
        }
    }
    #pragma unroll
    for (int ct = 0; ct < 16; ++ct)
        #pragma unroll
        for (int r = 0; r < 4; ++r)
            out[(size_t)(b * NN + tq * 128 + row0 + lg * 4 + r) * ND + ct * 16 + l16] = acc[ct][r];
}

extern "C" void kernel_launch(void* const* d_in, const int* in_sizes, int n_in,
                              void* d_out, int out_size, void* d_ws, size_t ws_size,
                              hipStream_t stream) {
    const float* h  = (const float*)d_in[0];
    const float* Wl = (const float*)d_in[2];
    const float* Wg = (const float*)d_in[3];
    const float* Wv = (const float*)d_in[4];
    const float* Wo = (const float*)d_in[5];
    float* out = (float*)d_out;

    uint8_t* base = (uint8_t*)d_ws;
    size_t off = 0;
    auto alloc = [&](size_t bytes) -> void* {
        void* r = base + off;
        off = (off + bytes + 255) & ~(size_t)255;
        return r;
    };
    const size_t bnd = (size_t)NB * NN * ND;
    _Float16* h16 = (_Float16*)alloc(bnd * 2);     // reused as vT after k_proj
    _Float16* Wlt = (_Float16*)alloc(ND * ND * 2);
    _Float16* Wgt = (_Float16*)alloc(ND * ND * 2);
    _Float16* Wvt = (_Float16*)alloc(ND * ND * 2);
    _Float16* Wot = (_Float16*)alloc(ND * ND * 2);
    _Float16* zn  = (_Float16*)alloc(bnd * 2);
    _Float16* zg  = (_Float16*)alloc(bnd * 2);
    _Float16* v16 = (_Float16*)alloc(bnd * 2);
    float*    sq  = (float*)alloc((size_t)NB * NN * 4);
    _Float16* P   = (_Float16*)alloc((size_t)NB * 2 * TRI * 16384 * 2);   // 69 MB
    float* degpart = (float*)alloc((size_t)NB * 2 * TRI * 256 * 4);       // 2.2 MB
    _Float16* vT = h16;                            // alias: h16 dead after k_proj

    // split-K chunking with ws fallback
    int CHUNK = 8, NCH = 0;
    for (;;) {
        NCH = 0;
        for (int t = 0; t < 32; ++t) NCH += (t + CHUNK) / CHUNK;
        if (off + (size_t)NB * NCH * 4 * 16384 * 2 + 256 <= ws_size || CHUNK >= 32) break;
        CHUNK *= 2;
    }
    _Float16* part = (_Float16*)alloc((size_t)NB * NCH * 4 * 16384 * 2);

    k_cvt_h<<<bnd / 4 / 256, 256, 0, stream>>>(h, h16);
    k_wt<<<dim3(ND, 4), 256, 0, stream>>>(Wl, Wg, Wv, Wo, Wlt, Wgt, Wvt, Wot);
    k_proj<<<dim3(NB * NN / 64, 3), 256, 0, stream>>>(h16, Wlt, Wgt, Wvt, zn, zg, v16, sq);
    k_tr<<<dim3(NN / 64, ND / 64, NB), 256, 0, stream>>>(v16, vT);
    k_score<<<NB * 2 * TRI, 256, 0, stream>>>(zn, zg, sq, P, degpart);
    k_pv<<<dim3(4 * NCH, NB), 256, 0, stream>>>(P, vT, part, CHUNK, NCH);
    k_combo<<<dim3(32, NB), 512, 0, stream>>>(part, degpart, Wot, out, CHUNK, NCH);
}

// Round 15
// 146.786 us; speedup vs baseline: 1.3219x; 1.1881x over previous
//
#include <hip/hip_runtime.h>
#include <cstdint>
#include <cstddef>

#define NB 2
#define NN 4096
#define ND 256
#define TRI 528   // 32*33/2 causal 128-tiles per (batch, mat)

typedef __attribute__((ext_vector_type(8))) _Float16 half8;
typedef __attribute__((ext_vector_type(4))) _Float16 half4;
typedef __attribute__((ext_vector_type(4))) float f32x4;

using gas_ptr = const __attribute__((address_space(1))) void*;
using las_ptr = __attribute__((address_space(3))) void*;

__device__ __host__ __forceinline__ int tri32(int t) { return t * (t + 1) / 2; }

__device__ __forceinline__ f32x4 mfma_16x16x32(half8 a, half8 b, f32x4 c) {
    return __builtin_amdgcn_mfma_f32_16x16x32_f16(a, b, c, 0, 0, 0);
}

#define BAR_V4() asm volatile("s_waitcnt vmcnt(4) lgkmcnt(0)\n\ts_barrier" ::: "memory")
#define BAR_V0() asm volatile("s_waitcnt vmcnt(0) lgkmcnt(0)\n\ts_barrier" ::: "memory")

// ---- 128-row x 64B staging side, paired-row swizzle (2 logical rows / 128B) ----
__device__ __forceinline__ void stage_side(const char* __restrict__ gb, size_t rstride,
                                           char* lb) {
    #pragma unroll
    for (int i = 0; i < 2; ++i) {
        const int o = threadIdx.x * 16 + i * 4096;
        const int rp = o >> 7;
        const int uw = (o & 127) ^ ((rp & 7) << 4);
        const int r = rp * 2 + (uw >> 6);
        const int c = uw & 63;
        __builtin_amdgcn_global_load_lds((gas_ptr)(gb + (size_t)r * rstride + c),
                                         (las_ptr)(lb + o), 16, 0, 0);
    }
}

__device__ __forceinline__ half8 ldsfrag(const char* lb, int row, int lg) {
    const int rp = row >> 1;
    const int x = (((row & 1) << 6) + (lg << 4)) ^ ((rp & 7) << 4);
    return *(const half8*)(lb + rp * 128 + x);
}

// ---------------- conversions ----------------
__global__ __launch_bounds__(256) void k_cvt_h(const float* __restrict__ h,
                                               _Float16* __restrict__ h16) {
    const int i = blockIdx.x * 256 + threadIdx.x;
    f32x4 v = ((const f32x4*)h)[i];
    half4 o;
    o[0] = (_Float16)v[0]; o[1] = (_Float16)v[1];
    o[2] = (_Float16)v[2]; o[3] = (_Float16)v[3];
    ((half4*)h16)[i] = o;
}

__global__ __launch_bounds__(256) void k_wt(const float* __restrict__ W0, const float* __restrict__ W1,
                                            const float* __restrict__ W2, const float* __restrict__ W3,
                                            _Float16* __restrict__ T0, _Float16* __restrict__ T1,
                                            _Float16* __restrict__ T2, _Float16* __restrict__ T3) {
    const int m = blockIdx.y;
    const float* W = m == 0 ? W0 : m == 1 ? W1 : m == 2 ? W2 : W3;
    _Float16* T    = m == 0 ? T0 : m == 1 ? T1 : m == 2 ? T2 : T3;
    const int k = blockIdx.x, j = threadIdx.x;
    T[j * ND + k] = (_Float16)W[k * ND + j];
}

// ---------------- GEMM core (projections) ----------------
__device__ __forceinline__ void gemm_core(const _Float16* __restrict__ A,
                                          const _Float16* __restrict__ Bt,
                                          int row0, int l16, int lg, f32x4 acc[16]) {
    #pragma unroll
    for (int i = 0; i < 16; ++i) acc[i] = (f32x4)0.0f;
    #pragma unroll
    for (int ks = 0; ks < 8; ++ks) {
        half8 a = *(const half8*)(A + (size_t)(row0 + l16) * ND + ks * 32 + lg * 8);
        #pragma unroll
        for (int ct = 0; ct < 16; ++ct) {
            half8 b = *(const half8*)(Bt + (size_t)(ct * 16 + l16) * ND + ks * 32 + lg * 8);
            acc[ct] = mfma_16x16x32(a, b, acc[ct]);
        }
    }
}

__global__ __launch_bounds__(256) void k_proj(const _Float16* __restrict__ h16,
                                              const _Float16* __restrict__ Wlt,
                                              const _Float16* __restrict__ Wgt,
                                              const _Float16* __restrict__ Wvt,
                                              _Float16* __restrict__ zn,
                                              _Float16* __restrict__ zg,
                                              _Float16* __restrict__ v16,
                                              float* __restrict__ sq) {
    const int mode = blockIdx.y;
    const _Float16* Bt = mode == 0 ? Wlt : mode == 1 ? Wgt : Wvt;
    _Float16* o16      = mode == 0 ? zn  : mode == 1 ? zg  : v16;
    const int w = threadIdx.x >> 6, l = threadIdx.x & 63;
    const int l16 = l & 15, lg = l >> 4;
    const int row0 = blockIdx.x * 64 + w * 16;
    f32x4 acc[16];
    gemm_core(h16, Bt, row0, l16, lg, acc);

    if (mode == 2) {
        #pragma unroll
        for (int ct = 0; ct < 16; ++ct)
            #pragma unroll
            for (int r = 0; r < 4; ++r)
                o16[(size_t)(row0 + lg * 4 + r) * ND + ct * 16 + l16] = (_Float16)acc[ct][r];
        return;
    }
    float n2[4] = {0.f, 0.f, 0.f, 0.f};
    #pragma unroll
    for (int ct = 0; ct < 16; ++ct)
        #pragma unroll
        for (int r = 0; r < 4; ++r) n2[r] += acc[ct][r] * acc[ct][r];
    #pragma unroll
    for (int m = 1; m < 16; m <<= 1) {
        #pragma unroll
        for (int r = 0; r < 4; ++r) n2[r] += __shfl_xor(n2[r], m);
    }
    if (mode == 0) {
        float ri[4];
        #pragma unroll
        for (int r = 0; r < 4; ++r) ri[r] = 1.0f / fmaxf(sqrtf(n2[r]), 1e-8f);
        #pragma unroll
        for (int ct = 0; ct < 16; ++ct)
            #pragma unroll
            for (int r = 0; r < 4; ++r)
                o16[(size_t)(row0 + lg * 4 + r) * ND + ct * 16 + l16] =
                    (_Float16)(acc[ct][r] * ri[r]);
    } else {
        #pragma unroll
        for (int ct = 0; ct < 16; ++ct)
            #pragma unroll
            for (int r = 0; r < 4; ++r)
                o16[(size_t)(row0 + lg * 4 + r) * ND + ct * 16 + l16] = (_Float16)acc[ct][r];
        if (l16 == 0) {
            #pragma unroll
            for (int r = 0; r < 4; ++r) sq[row0 + lg * 4 + r] = n2[r];
        }
    }
}

// v16 [b][n][d] -> vT [b][d][n]
__global__ __launch_bounds__(256) void k_tr(const _Float16* __restrict__ v16,
                                            _Float16* __restrict__ vT) {
    __shared__ _Float16 t[64][72];
    const int b = blockIdx.z, n0 = blockIdx.x * 64, d0 = blockIdx.y * 64;
    const int tj = threadIdx.x & 63, ti = threadIdx.x >> 6;
    #pragma unroll
    for (int i = 0; i < 16; ++i)
        t[ti + i * 4][tj] = v16[(size_t)(b * NN + n0 + ti + i * 4) * ND + d0 + tj];
    __syncthreads();
    #pragma unroll
    for (int i = 0; i < 16; ++i)
        vT[(size_t)(b * ND + d0 + ti + i * 4) * NN + n0 + tj] = t[tj][ti + i * 4];
}

// ---------------- score GEMM: R13 loop + LDS-transposed coalesced P store --------
__global__ __launch_bounds__(256, 3) void k_score(const _Float16* __restrict__ zn,
                                                  const _Float16* __restrict__ zg,
                                                  const float* __restrict__ sqg,
                                                  _Float16* __restrict__ P,
                                                  float* __restrict__ degpart) {
    const int orig = blockIdx.x;
    const int wgid = (orig & 7) * (NB * 2 * TRI / 8) + (orig >> 3);  // bijective XCD swizzle
    const int bm = wgid / TRI;
    int x = wgid % TRI, tq = 0;
    while (x > tq) { x -= (tq + 1); ++tq; }
    const int tk = x;
    const int b = bm >> 1, mat = bm & 1;
    const char* z = (const char*)((mat ? zg : zn) + (size_t)b * NN * ND);
    const float* sqb = sqg + (size_t)b * NN;
    const int w = threadIdx.x >> 6, lane = threadIdx.x & 63;
    const int l16 = lane & 15, lg = lane >> 4;
    const int wr = w >> 1, wc = w & 1;

    __shared__ char smem[49152];             // At[3][8192] | Bq[3][8192]; epilogue tile aliases
    char* At = smem;
    char* Bq = smem + 24576;

    const char* zk = z + (size_t)tk * 128 * 512;
    const char* zq = z + (size_t)tq * 128 * 512;

    auto STAGE = [&](int bufi, int s_) {
        stage_side(zk + s_ * 64, 512, At + bufi * 8192);
        stage_side(zq + s_ * 64, 512, Bq + bufi * 8192);
    };

    f32x4 acc[4][4];
    #pragma unroll
    for (int i = 0; i < 4; ++i)
        #pragma unroll
        for (int j = 0; j < 4; ++j) acc[i][j] = (f32x4)0.f;

    STAGE(0, 0);
    STAGE(1, 1);
    BAR_V4();                                  // stage(0) landed; stage(1) in flight

    #pragma unroll
    for (int s = 0; s < 8; ++s) {
        if (s < 6) STAGE((s + 2) % 3, s + 2);
        const int cb = s % 3;
        half8 a[4], bq[4];
        #pragma unroll
        for (int i = 0; i < 4; ++i) {
            a[i]  = ldsfrag(At + cb * 8192, wr * 64 + i * 16 + l16, lg);
            bq[i] = ldsfrag(Bq + cb * 8192, wc * 64 + i * 16 + l16, lg);
        }
        __builtin_amdgcn_s_setprio(1);
        #pragma unroll
        for (int di = 0; di < 4; ++di)
            #pragma unroll
            for (int qi = 0; qi < 4; ++qi)
                acc[di][qi] = mfma_16x16x32(a[di], bq[qi], acc[di][qi]);
        __builtin_amdgcn_s_setprio(0);
        if (s < 6) BAR_V4();
        else if (s == 6) BAR_V0();
    }

    // ---- epilogue: transform -> LDS (264B-stride tile), degree partials
    const int tile = tri32(tq) + tk;
    float dsum[4] = {0.f, 0.f, 0.f, 0.f};
    float sqq[4];
    if (mat) {
        #pragma unroll
        for (int qi = 0; qi < 4; ++qi)
            sqq[qi] = sqb[tq * 128 + wc * 64 + qi * 16 + l16];
    }
    __syncthreads();                           // compute LDS dead in all waves
    #pragma unroll
    for (int di = 0; di < 4; ++di) {
        const int kl = wr * 64 + di * 16 + lg * 4;
        const int kg = tk * 128 + kl;
        f32x4 sqk;
        if (mat) sqk = *(const f32x4*)(sqb + kg);
        #pragma unroll
        for (int qi = 0; qi < 4; ++qi) {
            const int qloc = wc * 64 + qi * 16 + l16;
            const int qg = tq * 128 + qloc;
            half4 hv;
            #pragma unroll
            for (int r = 0; r < 4; ++r) {
                const bool msk = (kg + r) < qg;        // causal + zero-diag
                float p;
                if (mat) p = msk ? __expf(-0.5f * (sqq[qi] + sqk[r] - 2.f * acc[di][qi][r])) : 0.f;
                else     p = msk ? fmaxf(acc[di][qi][r], 0.f) : 0.f;
                dsum[qi] += p;
                hv[r] = (_Float16)p;
            }
            *(half4*)(smem + qloc * 264 + kl * 2) = hv;
        }
    }
    #pragma unroll
    for (int qi = 0; qi < 4; ++qi) {
        dsum[qi] += __shfl_xor(dsum[qi], 16);
        dsum[qi] += __shfl_xor(dsum[qi], 32);
    }
    if (lg == 0) {
        #pragma unroll
        for (int qi = 0; qi < 4; ++qi)
            degpart[(size_t)(bm * TRI + tile) * 256 + wr * 128 + wc * 64 + qi * 16 + l16] = dsum[qi];
    }
    __syncthreads();
    // ---- coalesced P store: 256 thr x 16B x 8 iters = 32KB tile
    _Float16* Pt = P + (size_t)(bm * TRI + tile) * 16384;
    #pragma unroll
    for (int i = 0; i < 8; ++i) {
        const int o = threadIdx.x * 16 + i * 4096;
        const int row = o >> 8, col = o & 255;
        *(half8*)((char*)Pt + o) = *(const half8*)(smem + row * 264 + col);
    }
}

// ---------------- PV GEMM: R13 loop + LDS-transposed coalesced partial store -----
__global__ __launch_bounds__(256, 3) void k_pv(const _Float16* __restrict__ P,
                                               const _Float16* __restrict__ vT,
                                               _Float16* __restrict__ part,
                                               int CHUNK, int NCH) {
    const int dh = blockIdx.x & 1, mat = (blockIdx.x >> 1) & 1;
    int x = NCH - 1 - (blockIdx.x >> 2);     // reversed: long chunks dispatch first
    int tq = 0, cum = 0;
    for (;;) {
        const int nc = (tq + CHUNK) / CHUNK;  // ceil((tq+1)/CHUNK)
        if (x < nc) break;
        x -= nc; cum += nc; ++tq;
    }
    const int c = x;
    const int b = blockIdx.y;
    const int kt0 = c * CHUNK;
    const int ktE = (kt0 + CHUNK < tq + 1) ? kt0 + CHUNK : tq + 1;
    const int NS = (ktE - kt0) * 4;          // BK=32 steps

    const int w = threadIdx.x >> 6, lane = threadIdx.x & 63;
    const int l16 = lane & 15, lg = lane >> 4;
    const int wr = w >> 1, wc = w & 1;

    __shared__ char smem[49152];             // At[3] | Bp[3]; epilogue tile aliases
    char* At = smem;
    char* Bp = smem + 24576;

    const char* vTb = (const char*)(vT + (size_t)b * ND * NN) + (size_t)dh * 128 * (NN * 2);
    const char* Pbase = (const char*)(P + (size_t)((b * 2 + mat) * TRI + tri32(tq)) * 16384);

    auto STAGE = [&](int bufi, int j_) {
        const int kt = kt0 + (j_ >> 2), sub = j_ & 3;
        stage_side(vTb + (size_t)kt * 256 + sub * 64, (size_t)NN * 2, At + bufi * 8192);
        stage_side(Pbase + (size_t)kt * 32768 + sub * 64, 256, Bp + bufi * 8192);
    };

    f32x4 acc[4][4];
    #pragma unroll
    for (int i = 0; i < 4; ++i)
        #pragma unroll
        for (int j = 0; j < 4; ++j) acc[i][j] = (f32x4)0.f;

    STAGE(0, 0);
    STAGE(1, 1);
    BAR_V4();

    for (int s = 0; s < NS; ++s) {
        if (s + 2 < NS) STAGE((s + 2) % 3, s + 2);
        const int cb = s % 3;
        half8 a[4], bp[4];
        #pragma unroll
        for (int i = 0; i < 4; ++i) {
            a[i]  = ldsfrag(At + cb * 8192, wr * 64 + i * 16 + l16, lg);
            bp[i] = ldsfrag(Bp + cb * 8192, wc * 64 + i * 16 + l16, lg);
        }
        #pragma unroll
        for (int di = 0; di < 4; ++di)
            #pragma unroll
            for (int qi = 0; qi < 4; ++qi)
                acc[di][qi] = mfma_16x16x32(a[di], bp[qi], acc[di][qi]);
        if (s + 2 < NS) BAR_V4();
        else if (s + 1 < NS) BAR_V0();
    }

    __syncthreads();                           // all waves done reading compute LDS
    #pragma unroll
    for (int di = 0; di < 4; ++di) {
        const int dl = wr * 64 + di * 16 + lg * 4;
        #pragma unroll
        for (int qi = 0; qi < 4; ++qi) {
            const int qloc = wc * 64 + qi * 16 + l16;
            half4 hv;
            #pragma unroll
            for (int r = 0; r < 4; ++r) hv[r] = (_Float16)acc[di][qi][r];
            *(half4*)(smem + qloc * 264 + dl * 2) = hv;
        }
    }
    __syncthreads();
    _Float16* sl = part + (size_t)(((b * NCH + cum + c) * 2 + dh) * 2 + mat) * 16384;
    #pragma unroll
    for (int i = 0; i < 8; ++i) {
        const int o = threadIdx.x * 16 + i * 4096;
        const int row = o >> 8, col = o & 255;
        *(half8*)((char*)sl + o) = *(const half8*)(smem + row * 264 + col);
    }
}

// ---------------- fused combine + normalize + @Wo -> out (row-quartered) --------
// grid (32 tq x 4 row-quarters, NB), 256 thr. Each block: 32 q-rows x full 256 d.
__global__ __launch_bounds__(256) void k_combo(const _Float16* __restrict__ part,
                                               const float* __restrict__ degpart,
                                               const _Float16* __restrict__ Wot,
                                               float* __restrict__ out,
                                               int CHUNK, int NCH) {
    const int tq = blockIdx.x >> 2, rq = blockIdx.x & 3, b = blockIdx.y;
    const int r0 = rq * 32;
    __shared__ _Float16 ot_t[32][264];       // 528B rows (2-way/free on col reads)
    __shared__ float rl[32], rg[32];

    if (threadIdx.x < 64) {
        const int i = threadIdx.x & 31;
        const int m = threadIdx.x >> 5;
        const float* dp = degpart + (size_t)((b * 2 + m) * TRI + tri32(tq)) * 256 + r0 + i;
        float d = 0.f;
        for (int tk = 0; tk <= tq; ++tk)
            d += dp[(size_t)tk * 256] + dp[(size_t)tk * 256 + 128];
        (m ? rg : rl)[i] = (m ? 0.1f : 0.9f) / fmaxf(d, 1e-8f);
    }
    __syncthreads();

    int cum = 0;
    for (int t = 0; t < tq; ++t) cum += (t + CHUNK) / CHUNK;
    const int nc = (tq + CHUNK) / CHUNK;
    // combine this block's 32 rows x 256 d (= 8192 f16; 4096 per dh half)
    #pragma unroll
    for (int it = 0; it < 4; ++it) {
        const int f = it * 2048 + threadIdx.x * 8;
        const int dh = f >> 12, rem = f & 4095;
        const int row = rem >> 7, col = rem & 127;
        float s_l[8] = {0,0,0,0,0,0,0,0}, s_g[8] = {0,0,0,0,0,0,0,0};
        for (int c = 0; c < nc; ++c) {
            const size_t so = (size_t)(((b * NCH + cum + c) * 2 + dh) * 2) * 16384
                              + (size_t)(r0 + row) * 128 + col;
            half8 xl = *(const half8*)(part + so);
            half8 xg = *(const half8*)(part + so + 16384);
            #pragma unroll
            for (int k = 0; k < 8; ++k) { s_l[k] += (float)xl[k]; s_g[k] += (float)xg[k]; }
        }
        half8 o;
        #pragma unroll
        for (int k = 0; k < 8; ++k)
            o[k] = (_Float16)(rl[row] * s_l[k] + rg[row] * s_g[k]);
        *(half8*)&ot_t[row][dh * 128 + col] = o;
    }
    __syncthreads();

    // GEMM: wave w -> rows (w&1)*16, cols (w>>1)*128
    const int w = threadIdx.x >> 6, l = threadIdx.x & 63;
    const int l16 = l & 15, lg = l >> 4;
    const int row0 = (w & 1) * 16;
    const int c0 = (w >> 1) * 128;
    f32x4 acc[8];
    #pragma unroll
    for (int i = 0; i < 8; ++i) acc[i] = (f32x4)0.f;
    #pragma unroll
    for (int ks = 0; ks < 8; ++ks) {
        half8 a = *(const half8*)&ot_t[row0 + l16][ks * 32 + lg * 8];
        #pragma unroll
        for (int ct = 0; ct < 8; ++ct) {
            half8 bw = *(const half8*)(Wot + (size_t)(c0 + ct * 16 + l16) * ND + ks * 32 + lg * 8);
            acc[ct] = mfma_16x16x32(a, bw, acc[ct]);
        }
    }
    #pragma unroll
    for (int ct = 0; ct < 8; ++ct)
        #pragma unroll
        for (int r = 0; r < 4; ++r)
            out[(size_t)(b * NN + tq * 128 + r0 + row0 + lg * 4 + r) * ND + c0 + ct * 16 + l16] = acc[ct][r];
}

extern "C" void kernel_launch(void* const* d_in, const int* in_sizes, int n_in,
                              void* d_out, int out_size, void* d_ws, size_t ws_size,
                              hipStream_t stream) {
    const float* h  = (const float*)d_in[0];
    const float* Wl = (const float*)d_in[2];
    const float* Wg = (const float*)d_in[3];
    const float* Wv = (const float*)d_in[4];
    const float* Wo = (const float*)d_in[5];
    float* out = (float*)d_out;

    uint8_t* base = (uint8_t*)d_ws;
    size_t off = 0;
    auto alloc = [&](size_t bytes) -> void* {
        void* r = base + off;
        off = (off + bytes + 255) & ~(size_t)255;
        return r;
    };
    const size_t bnd = (size_t)NB * NN * ND;
    _Float16* h16 = (_Float16*)alloc(bnd * 2);     // reused as vT after k_proj
    _Float16* Wlt = (_Float16*)alloc(ND * ND * 2);
    _Float16* Wgt = (_Float16*)alloc(ND * ND * 2);
    _Float16* Wvt = (_Float16*)alloc(ND * ND * 2);
    _Float16* Wot = (_Float16*)alloc(ND * ND * 2);
    _Float16* zn  = (_Float16*)alloc(bnd * 2);
    _Float16* zg  = (_Float16*)alloc(bnd * 2);
    _Float16* v16 = (_Float16*)alloc(bnd * 2);
    float*    sq  = (float*)alloc((size_t)NB * NN * 4);
    _Float16* P   = (_Float16*)alloc((size_t)NB * 2 * TRI * 16384 * 2);   // 69 MB
    float* degpart = (float*)alloc((size_t)NB * 2 * TRI * 256 * 4);       // 2.2 MB
    _Float16* vT = h16;                            // alias: h16 dead after k_proj

    // split-K chunking with ws fallback
    int CHUNK = 8, NCH = 0;
    for (;;) {
        NCH = 0;
        for (int t = 0; t < 32; ++t) NCH += (t + CHUNK) / CHUNK;
        if (off + (size_t)NB * NCH * 4 * 16384 * 2 + 256 <= ws_size || CHUNK >= 32) break;
        CHUNK *= 2;
    }
    _Float16* part = (_Float16*)alloc((size_t)NB * NCH * 4 * 16384 * 2);

    k_cvt_h<<<bnd / 4 / 256, 256, 0, stream>>>(h, h16);
    k_wt<<<dim3(ND, 4), 256, 0, stream>>>(Wl, Wg, Wv, Wo, Wlt, Wgt, Wvt, Wot);
    k_proj<<<dim3(NB * NN / 64, 3), 256, 0, stream>>>(h16, Wlt, Wgt, Wvt, zn, zg, v16, sq);
    k_tr<<<dim3(NN / 64, ND / 64, NB), 256, 0, stream>>>(v16, vT);
    k_score<<<NB * 2 * TRI, 256, 0, stream>>>(zn, zg, sq, P, degpart);
    k_pv<<<dim3(4 * NCH, NB), 256, 0, stream>>>(P, vT, part, CHUNK, NCH);
    k_combo<<<dim3(128, NB), 256, 0, stream>>>(part, degpart, Wot, out, CHUNK, NCH);
}